// Round 2
// baseline (5594.695 us; speedup 1.0000x reference)
//
#include <hip/hip_runtime.h>

#define HH 128
#define WW 128
#define HWX (HH*WW)

// ---------------------------------------------------------------------------
// Generic 3x3 SAME conv, NCHW, H=W=128.
// Block 256 threads. Tile 32x32 (4 px/thread: rows ty, ty+8, ty+16, ty+24).
// grid = (4, 4, nimg * nslice); slice selects OCB output channels.
// CRMODE: input channels 0-63 come from ref image (b*5+2) of a 10-image
// buffer, channels 64-127 from supp image (b*5+n) -- fused concat.
// ---------------------------------------------------------------------------
template<int CIN, int CK, int OCB, bool RELU, bool ADD, bool CRMODE>
__global__ __launch_bounds__(256) void conv3x3_k(
    const float* __restrict__ in, const float* __restrict__ wgt,
    const float* __restrict__ bias, const float* __restrict__ res,
    float* __restrict__ out, int Cout, int nslice, int img_in0, int img_out0)
{
  __shared__ __align__(16) float s_in[CK][34][34];
  __shared__ __align__(16) float s_w[CK * 9 * OCB];

  const int tid = threadIdx.x;
  const int tx = tid & 31;
  const int ty = tid >> 5;                  // 0..7
  const int iz = blockIdx.z / nslice;
  const int slice = blockIdx.z % nslice;
  const int oc0 = slice * OCB;
  const int x0 = blockIdx.x * 32;
  const int y0 = blockIdx.y * 32;

  float acc[4][OCB];
#pragma unroll
  for (int r = 0; r < 4; ++r)
#pragma unroll
    for (int o = 0; o < OCB; ++o) acc[r][o] = 0.f;

  int bb = 0, nn = 0;
  const float* inb = in;
  if (CRMODE) {
    int j = img_in0 + iz;
    bb = j >> 2;
    int ns = j & 3;
    nn = ns < 2 ? ns : ns + 1;
  } else {
    inb = in + (long)(img_in0 + iz) * CIN * HWX;
  }

  for (int c0 = 0; c0 < CIN; c0 += CK) {
    __syncthreads();
    // stage input tile (halo, zero-padded at image border)
    for (int idx = tid; idx < CK * 34 * 34; idx += 256) {
      int c = idx / 1156;
      int rem = idx % 1156;
      int iy = rem / 34, ix = rem % 34;
      int gy = y0 + iy - 1, gx = x0 + ix - 1;
      float v = 0.f;
      if (gy >= 0 && gy < HH && gx >= 0 && gx < WW) {
        if (CRMODE) {
          int ch = c0 + c;
          int simg = (ch < 64) ? (bb * 5 + 2) : (bb * 5 + nn);
          v = in[((long)simg * 64 + (ch & 63)) * HWX + gy * WW + gx];
        } else {
          v = inb[(long)(c0 + c) * HWX + gy * WW + gx];
        }
      }
      s_in[c][iy][ix] = v;
    }
    // stage weights as [c][k][oc]
    for (int idx = tid; idx < CK * 9 * OCB; idx += 256) {
      int oc = idx % OCB;
      int ck = idx / OCB;
      int c = ck / 9, k = ck % 9;
      int ocg = oc0 + oc;
      float v = 0.f;
      if (ocg < Cout) v = wgt[((long)ocg * CIN + c0 + c) * 9 + k];
      s_w[idx] = v;
    }
    __syncthreads();

    for (int c = 0; c < CK; ++c) {
#pragma unroll
      for (int k = 0; k < 9; ++k) {
        const int ky = k / 3, kx = k % 3;
        float v0 = s_in[c][ty + ky][tx + kx];
        float v1 = s_in[c][ty + 8 + ky][tx + kx];
        float v2 = s_in[c][ty + 16 + ky][tx + kx];
        float v3 = s_in[c][ty + 24 + ky][tx + kx];
        const float4* wp = (const float4*)&s_w[(c * 9 + k) * OCB];
#pragma unroll
        for (int o4 = 0; o4 < OCB / 4; ++o4) {
          float4 w4 = wp[o4];
          acc[0][o4 * 4 + 0] += v0 * w4.x; acc[0][o4 * 4 + 1] += v0 * w4.y;
          acc[0][o4 * 4 + 2] += v0 * w4.z; acc[0][o4 * 4 + 3] += v0 * w4.w;
          acc[1][o4 * 4 + 0] += v1 * w4.x; acc[1][o4 * 4 + 1] += v1 * w4.y;
          acc[1][o4 * 4 + 2] += v1 * w4.z; acc[1][o4 * 4 + 3] += v1 * w4.w;
          acc[2][o4 * 4 + 0] += v2 * w4.x; acc[2][o4 * 4 + 1] += v2 * w4.y;
          acc[2][o4 * 4 + 2] += v2 * w4.z; acc[2][o4 * 4 + 3] += v2 * w4.w;
          acc[3][o4 * 4 + 0] += v3 * w4.x; acc[3][o4 * 4 + 1] += v3 * w4.y;
          acc[3][o4 * 4 + 2] += v3 * w4.z; acc[3][o4 * 4 + 3] += v3 * w4.w;
        }
      }
    }
  }

#pragma unroll
  for (int o = 0; o < OCB; ++o) {
    int ocg = oc0 + o;
    if (ocg < Cout) {
      float b = bias ? bias[ocg] : 0.f;
      long base = ((long)(img_out0 + iz) * Cout + ocg) * HWX;
#pragma unroll
      for (int r = 0; r < 4; ++r) {
        int y = y0 + ty + 8 * r;
        float v = acc[r][o] + b;
        if (RELU) v = fmaxf(v, 0.f);
        long ia = base + (long)y * WW + x0 + tx;
        if (ADD) v += res[ia];
        out[ia] = v;
      }
    }
  }
}

// ---------------------------------------------------------------------------
// Regroup NCHW -> [img][g][y][x][c8] (channels-last within group of 8).
// supp_mode: source images are the 8 non-center images of the 10-image buffer.
// ---------------------------------------------------------------------------
__global__ __launch_bounds__(256) void regroup_k(
    const float* __restrict__ src, float* __restrict__ dst, int supp_mode)
{
  int idx = blockIdx.x * 256 + threadIdx.x;   // 8388608 total, exact
  int c = idx & 7;
  int p = (idx >> 3) & 16383;
  int g = (idx >> 17) & 7;
  int img = idx >> 20;
  int simg = img;
  if (supp_mode) {
    int b = img >> 2, ns = img & 3;
    simg = b * 5 + (ns < 2 ? ns : ns + 1);
  }
  dst[idx] = src[((simg * 64 + g * 8 + c) * HWX) + p];
}

// ---------------------------------------------------------------------------
// Bilinear sample of 8 grouped channels with zero padding outside [0,127]^2.
// ---------------------------------------------------------------------------
__device__ __forceinline__ void bilin8(const float* __restrict__ sg,
                                       float py, float px, float* sv)
{
  float y0f = floorf(py), x0f = floorf(px);
  float wy = py - y0f, wx = px - x0f;
  float y1f = y0f + 1.f, x1f = x0f + 1.f;
  float my0 = (y0f >= 0.f && y0f <= 127.f) ? 1.f : 0.f;
  float my1 = (y1f >= 0.f && y1f <= 127.f) ? 1.f : 0.f;
  float mx0 = (x0f >= 0.f && x0f <= 127.f) ? 1.f : 0.f;
  float mx1 = (x1f >= 0.f && x1f <= 127.f) ? 1.f : 0.f;
  int yi0 = (int)fminf(fmaxf(y0f, 0.f), 127.f);
  int yi1 = (int)fminf(fmaxf(y1f, 0.f), 127.f);
  int xi0 = (int)fminf(fmaxf(x0f, 0.f), 127.f);
  int xi1 = (int)fminf(fmaxf(x1f, 0.f), 127.f);
  float w00 = (1.f - wy) * (1.f - wx) * my0 * mx0;
  float w01 = (1.f - wy) * wx * my0 * mx1;
  float w10 = wy * (1.f - wx) * my1 * mx0;
  float w11 = wy * wx * my1 * mx1;
  const float4* p00 = (const float4*)(sg + ((long)yi0 * WW + xi0) * 8);
  const float4* p01 = (const float4*)(sg + ((long)yi0 * WW + xi1) * 8);
  const float4* p10 = (const float4*)(sg + ((long)yi1 * WW + xi0) * 8);
  const float4* p11 = (const float4*)(sg + ((long)yi1 * WW + xi1) * 8);
  float4 a00 = p00[0], b00 = p00[1];
  float4 a01 = p01[0], b01 = p01[1];
  float4 a10 = p10[0], b10 = p10[1];
  float4 a11 = p11[0], b11 = p11[1];
  sv[0] = w00 * a00.x + w01 * a01.x + w10 * a10.x + w11 * a11.x;
  sv[1] = w00 * a00.y + w01 * a01.y + w10 * a10.y + w11 * a11.y;
  sv[2] = w00 * a00.z + w01 * a01.z + w10 * a10.z + w11 * a11.z;
  sv[3] = w00 * a00.w + w01 * a01.w + w10 * a10.w + w11 * a11.w;
  sv[4] = w00 * b00.x + w01 * b01.x + w10 * b10.x + w11 * b11.x;
  sv[5] = w00 * b00.y + w01 * b01.y + w10 * b10.y + w11 * b11.y;
  sv[6] = w00 * b00.z + w01 * b01.z + w10 * b10.z + w11 * b11.z;
  sv[7] = w00 * b00.w + w01 * b01.w + w10 * b10.w + w11 * b11.w;
}

// ---------------------------------------------------------------------------
// Deformable conv: G=8, Cpg=8, K2=9. srcg: [8 img][8 g][128][128][8 c].
// off (LOCAL imgs): [chunk][144][HW]. Block 256 = 32x16 px (2 px/thread),
// 32 out-ch per slice (2 slices). grid (4, 8, chunk*2). img = img0 + z/2.
// ---------------------------------------------------------------------------
__global__ __launch_bounds__(256) void deform_k(
    const float* __restrict__ srcg, const float* __restrict__ off,
    const float* __restrict__ wgt, float* __restrict__ out, int img0)
{
  __shared__ __align__(16) float s_w[8 * 9 * 32];
  const int tid = threadIdx.x;
  const int tx = tid & 31, ty = tid >> 5;
  const int iz = blockIdx.z >> 1;
  const int slice = blockIdx.z & 1;
  const int oc0 = slice * 32;
  const int img = img0 + iz;
  const int x = blockIdx.x * 32 + tx;
  const int ya = blockIdx.y * 16 + ty;
  const int yb = ya + 8;

  float acc0[32], acc1[32];
#pragma unroll
  for (int o = 0; o < 32; ++o) { acc0[o] = 0.f; acc1[o] = 0.f; }

  for (int g = 0; g < 8; ++g) {
    __syncthreads();
    for (int idx = tid; idx < 8 * 9 * 32; idx += 256) {
      int oc = idx & 31;
      int ck = idx >> 5;
      int cpg = ck / 9, k = ck % 9;
      s_w[idx] = wgt[((long)(oc0 + oc) * 64 + g * 8 + cpg) * 9 + k];
    }
    __syncthreads();

    const float* offp = off + ((long)iz * 144 + g * 18) * HWX + x;
    const float* sg = srcg + (long)(img * 8 + g) * HWX * 8;

#pragma unroll 1
    for (int k = 0; k < 9; ++k) {
      float dy0 = offp[(2 * k) * HWX + ya * WW];
      float dx0 = offp[(2 * k + 1) * HWX + ya * WW];
      float dy1 = offp[(2 * k) * HWX + yb * WW];
      float dx1 = offp[(2 * k + 1) * HWX + yb * WW];
      float kyf = (float)(k / 3 - 1), kxf = (float)(k % 3 - 1);
      float sv0[8], sv1[8];
      bilin8(sg, dy0 + (float)ya + kyf, dx0 + (float)x + kxf, sv0);
      bilin8(sg, dy1 + (float)yb + kyf, dx1 + (float)x + kxf, sv1);
#pragma unroll
      for (int cpg = 0; cpg < 8; ++cpg) {
        float u0 = sv0[cpg], u1 = sv1[cpg];
        const float4* wp = (const float4*)&s_w[(cpg * 9 + k) * 32];
#pragma unroll
        for (int o4 = 0; o4 < 8; ++o4) {
          float4 w4 = wp[o4];
          acc0[o4 * 4 + 0] += u0 * w4.x; acc1[o4 * 4 + 0] += u1 * w4.x;
          acc0[o4 * 4 + 1] += u0 * w4.y; acc1[o4 * 4 + 1] += u1 * w4.y;
          acc0[o4 * 4 + 2] += u0 * w4.z; acc1[o4 * 4 + 2] += u1 * w4.z;
          acc0[o4 * 4 + 3] += u0 * w4.w; acc1[o4 * 4 + 3] += u1 * w4.w;
        }
      }
    }
  }

  long obase = ((long)img * 64 + oc0) * HWX + x;
#pragma unroll
  for (int o = 0; o < 32; ++o) {
    out[obase + (long)o * HWX + (long)ya * WW] = acc0[o];
    out[obase + (long)o * HWX + (long)yb * WW] = acc1[o];
  }
}

// ---------------------------------------------------------------------------
// Final assembly: d_out = [lrs (2,5,3,128,128)] ++ [feats (2,5,64,128,128)]
// ---------------------------------------------------------------------------
__global__ __launch_bounds__(256) void assemble_k(
    const float* __restrict__ x, const float* __restrict__ im,
    const float* __restrict__ out0, const float* __restrict__ fea,
    float* __restrict__ out)
{
  int idx = blockIdx.x * 256 + threadIdx.x;
  if (idx < 491520) {
    int within = idx % 49152;
    int n = (idx / 49152) % 5;
    int b = idx / (49152 * 5);
    float v;
    if (n == 2) v = x[(b * 5 + 2) * 49152 + within];
    else {
      int j = b * 4 + (n < 2 ? n : n - 1);
      v = im[j * 49152 + within];
    }
    out[idx] = v;
  } else if (idx < 10977280) {
    int idx2 = idx - 491520;
    int within = idx2 % 1048576;
    int n = (idx2 / 1048576) % 5;
    int b = idx2 / (1048576 * 5);
    float v;
    if (n == 2) v = out0[(b * 5 + 2) * 1048576 + within];
    else {
      int j = b * 4 + (n < 2 ? n : n - 1);
      v = fea[j * 1048576 + within];
    }
    out[idx] = v;
  }
}

// ---------------------------------------------------------------------------
extern "C" void kernel_launch(void* const* d_in, const int* in_sizes, int n_in,
                              void* d_out, int out_size, void* d_ws, size_t ws_size,
                              hipStream_t stream) {
  const float* x   = (const float*)d_in[0];
  const float* cfw = (const float*)d_in[1];
  const float* cfb = (const float*)d_in[2];
  const float* rw1 = (const float*)d_in[3];
  const float* rb1 = (const float*)d_in[4];
  const float* rw2 = (const float*)d_in[5];
  const float* rb2 = (const float*)d_in[6];
  const float* crw = (const float*)d_in[7];
  const float* crb = (const float*)d_in[8];
  const float* ofw = (const float*)d_in[9];
  const float* ofb = (const float*)d_in[10];
  const float* dcw = (const float*)d_in[11];
  const float* rcw = (const float*)d_in[12];
  const float* rcb = (const float*)d_in[13];
  float* out = (float*)d_out;

  // Workspace pool (floats):
  //   A   : res output (10,64,HW)  10,485,760
  //   C   : fea ping   ( 8,64,HW)   8,388,608
  //   D   : grouped    ( 8,8,HW,8)  8,388,608   (also: im alias at the end)
  //   F   : fea3       ( 8,64,HW)   8,388,608
  //   OFF : offsets    (chunk,144,HW) chunk*2,359,296
  //   r (res temp) aliases C..F (25.1M >= 10.5M needed)
  float* A = (float*)d_ws;
  float* C = A + 10485760;
  float* D = C + 8388608;
  float* F = D + 8388608;
  float* OFF = F + 8388608;
  float* r = C;
  float* im = D;

  // pick offset-buffer image chunk so everything fits in ws_size
  const size_t fixedF = 10485760UL + 3UL * 8388608UL;
  int chunk = 8;
  while (chunk > 1 && (fixedF + (size_t)chunk * 2359296UL) * sizeof(float) > ws_size)
    chunk >>= 1;

  dim3 blk(256);

  // conv_first + ReLU : x (10,3,HW) -> A (10,64,HW)
  conv3x3_k<3, 3, 16, true, false, false><<<dim3(4, 4, 40), blk, 0, stream>>>(
      x, cfw, cfb, nullptr, A, 64, 4, 0, 0);

  // 5 residual blocks (in-place on A; temp r)
  for (int i = 0; i < 5; ++i) {
    conv3x3_k<64, 8, 16, true, false, false><<<dim3(4, 4, 40), blk, 0, stream>>>(
        A, rw1 + (long)i * 36864, rb1 + i * 64, nullptr, r, 64, 4, 0, 0);
    conv3x3_k<64, 8, 16, false, true, false><<<dim3(4, 4, 40), blk, 0, stream>>>(
        r, rw2 + (long)i * 36864, rb2 + i * 64, A, A, 64, 4, 0, 0);
  }

  // cr conv with fused concat(ref,supp): A -> C (fea0)
  conv3x3_k<128, 8, 16, false, false, true><<<dim3(4, 4, 32), blk, 0, stream>>>(
      A, crw, crb, nullptr, C, 64, 4, 0, 0);

  // offset conv + deform, chunked over images
  auto off_deform = [&](const float* fea_in, const float* grouped,
                        const float* ow, const float* ob, const float* dw,
                        float* outp) {
    for (int i0 = 0; i0 < 8; i0 += chunk) {
      conv3x3_k<64, 8, 16, false, false, false>
          <<<dim3(4, 4, chunk * 9), blk, 0, stream>>>(
              fea_in, ow, ob, nullptr, OFF, 144, 9, i0, 0);
      deform_k<<<dim3(4, 8, chunk * 2), blk, 0, stream>>>(
          grouped, OFF, dw, outp, i0);
    }
  };

  // layer 0: fea1 = deform(fea0, conv(fea0))        C -> C
  regroup_k<<<32768, blk, 0, stream>>>(C, D, 0);
  off_deform(C, D, ofw, ofb, dcw, C);

  // layer 1: fea2 = deform(fea1, conv(fea1))        C -> C
  regroup_k<<<32768, blk, 0, stream>>>(C, D, 0);
  off_deform(C, D, ofw + 82944, ofb + 144, dcw + 36864, C);

  // layer 2: fea3 = deform(supp, conv(fea2))        (A supp, C) -> F
  regroup_k<<<32768, blk, 0, stream>>>(A, D, 1);
  off_deform(C, D, ofw + 2 * 82944, ofb + 2 * 144, dcw + 2 * 36864, F);

  // layer 3: aligned = deform(fea3, conv(fea3))     F -> C
  regroup_k<<<32768, blk, 0, stream>>>(F, D, 0);
  off_deform(F, D, ofw + 3 * 82944, ofb + 3 * 144, dcw + 3 * 36864, C);

  // recon conv: aligned -> im (8,3,HW), stored in D (dead)
  conv3x3_k<64, 8, 4, false, false, false><<<dim3(4, 4, 8), blk, 0, stream>>>(
      C, rcw, rcb, nullptr, im, 3, 1, 0, 0);

  // assemble outputs
  assemble_k<<<42880, blk, 0, stream>>>(x, im, A, F, out);
}

// Round 4
// 2815.020 us; speedup vs baseline: 1.9874x; 1.9874x over previous
//
#include <hip/hip_runtime.h>

#define HH 128
#define WW 128
#define HWX (HH*WW)

using f32x4 = __attribute__((ext_vector_type(4))) float;
using f16x8 = __attribute__((ext_vector_type(8))) _Float16;

__device__ __forceinline__ unsigned short f16bits(_Float16 h) {
  union { _Float16 f; unsigned short u; } v; v.f = h; return v.u;
}

// chunk swizzle: position pos (64B row of 32 f16), chunk q (16B of 8 f16)
__device__ __forceinline__ int swz(int pos, int q) {
  return pos * 32 + (((q + pos + (pos >> 2)) & 3) << 3);
}

// ---------------------------------------------------------------------------
// Weight prep: OIHW fp32 -> [layer][kpos][O][I] split-fp16 (hi + lo arenas)
// ---------------------------------------------------------------------------
__global__ __launch_bounds__(256) void wprep_k(
    const float* __restrict__ src, unsigned short* __restrict__ dhi,
    unsigned short* __restrict__ dlo, int O, int I, int L)
{
  int idx = blockIdx.x * 256 + threadIdx.x;
  int tot = L * O * I * 9;
  if (idx >= tot) return;
  int per = O * I * 9;
  int layer = idx / per;
  int r = idx - layer * per;
  int o = r / (I * 9);
  int r2 = r - o * (I * 9);
  int i = r2 / 9, k = r2 - i * 9;
  float v = src[idx];
  _Float16 h = (_Float16)v;
  _Float16 l = (_Float16)(v - (float)h);
  long di = (long)layer * per + ((long)k * O + o) * I + i;
  dhi[di] = f16bits(h);
  dlo[di] = f16bits(l);
}

// ---------------------------------------------------------------------------
// Split-fp16 MFMA implicit-GEMM 3x3 SAME conv. Block 256 thr = 4 waves.
// px tile 32x8; wave: 64 px (rows 2wv,2wv+1 x halves) x OCB oc.
// Each logical product = 3 MFMAs: Ahi*Blo + Alo*Bhi + Ahi*Bhi (fp32 acc)
// => fp32-equivalent precision (~2^-22 per-term rel error).
// CRMODE: input ch 0-63 = ref img (b*5+2), 64-127 = supp img of 10-img buffer.
// ---------------------------------------------------------------------------
template<int CBLK, int NFRAG, bool RELU, bool ADD, bool CRMODE>
__global__ __launch_bounds__(256, 2) void conv_mfma_k(
    const float* __restrict__ in, const unsigned short* __restrict__ whi,
    const unsigned short* __restrict__ wlo,
    const float* __restrict__ bias, const float* __restrict__ res,
    float* __restrict__ out, int Cout, int nslice, int img_in0, int img_out0)
{
  constexpr int CIN = CBLK * 32;
  constexpr int OCB = NFRAG * 16;
  constexpr int WHALF = 9 * OCB * 32;
  __shared__ __align__(16) unsigned short s_in[2 * 10880];   // 10x34 halo, hi|lo
  __shared__ __align__(16) unsigned short s_w[2 * WHALF];    // hi|lo

  const int tid = threadIdx.x;
  const int lane = tid & 63;
  const int wv = tid >> 6;
  const int m16 = lane & 15, q = lane >> 4;
  const int iz = blockIdx.z / nslice, slice = blockIdx.z % nslice;
  const int oc_blk0 = slice * OCB;
  const int x0 = blockIdx.x * 32, y0 = blockIdx.y * 8;

  f32x4 acc[4][NFRAG];
#pragma unroll
  for (int mt = 0; mt < 4; ++mt)
#pragma unroll
    for (int nt = 0; nt < NFRAG; ++nt)
#pragma unroll
      for (int i = 0; i < 4; ++i) acc[mt][nt][i] = 0.f;

  int bb = 0, nn = 0;
  const float* inb = in;
  if (CRMODE) {
    int j = img_in0 + iz;
    bb = j >> 2;
    int ns = j & 3;
    nn = ns < 2 ? ns : ns + 1;
  } else {
    inb = in + (long)(img_in0 + iz) * CIN * HWX;
  }

  for (int cb = 0; cb < CBLK; ++cb) {
    const int c0 = cb * 32;
    __syncthreads();
    // ---- stage input tile: fp32 -> (hi,lo) fp16, channels-last, swizzled ----
    for (int t = tid; t < 1360; t += 256) {
      int qq = t / 340, pos = t - qq * 340;
      int iy = pos / 34, ix = pos - iy * 34;
      int gy = y0 + iy - 1, gx = x0 + ix - 1;
      bool inr = (gy >= 0 && gy < HH && gx >= 0 && gx < WW);
      const float* src;
      if (CRMODE) {
        int ch = c0 + qq * 8;
        int simg = (ch < 64) ? (bb * 5 + 2) : (bb * 5 + nn);
        src = in + ((long)simg * 64 + (ch & 63)) * HWX + gy * WW + gx;
      } else {
        src = inb + (long)(c0 + qq * 8) * HWX + gy * WW + gx;
      }
      unsigned hi4[4], lo4[4];
#pragma unroll
      for (int j2 = 0; j2 < 4; ++j2) {
        unsigned short hs[2], ls[2];
#pragma unroll
        for (int j = 0; j < 2; ++j) {
          float v = inr ? src[(long)(j2 * 2 + j) * HWX] : 0.f;
          _Float16 h = (_Float16)v;
          _Float16 l = (_Float16)(v - (float)h);
          hs[j] = f16bits(h); ls[j] = f16bits(l);
        }
        hi4[j2] = (unsigned)hs[0] | ((unsigned)hs[1] << 16);
        lo4[j2] = (unsigned)ls[0] | ((unsigned)ls[1] << 16);
      }
      *(uint4*)(s_in + swz(pos, qq)) = make_uint4(hi4[0], hi4[1], hi4[2], hi4[3]);
      *(uint4*)(s_in + 10880 + swz(pos, qq)) =
          make_uint4(lo4[0], lo4[1], lo4[2], lo4[3]);
    }
    // ---- stage weights (split arenas [kpos][Cout][CIN] -> LDS swizzled) ----
    for (int t = tid; t < 9 * OCB * 4; t += 256) {
      int qq = t / (9 * OCB), pw = t - qq * (9 * OCB);
      int kp = pw / OCB, ocl = pw - kp * OCB;
      long so = ((long)kp * Cout + oc_blk0 + ocl) * CIN + c0 + qq * 8;
      *(uint4*)(s_w + swz(pw, qq)) = *(const uint4*)(whi + so);
      *(uint4*)(s_w + WHALF + swz(pw, qq)) = *(const uint4*)(wlo + so);
    }
    __syncthreads();

    // ---- K loop: 9 kernel positions x 32 channels, 3 MFMAs per logical ----
#pragma unroll
    for (int kp = 0; kp < 9; ++kp) {
      const int dy = kp / 3, dx = kp - dy * 3;
      f16x8 bhi[NFRAG], blo[NFRAG];
#pragma unroll
      for (int nt = 0; nt < NFRAG; ++nt) {
        int pw = kp * OCB + nt * 16 + m16;
        bhi[nt] = *(const f16x8*)(s_w + swz(pw, q));
        blo[nt] = *(const f16x8*)(s_w + WHALF + swz(pw, q));
      }
#pragma unroll
      for (int mt = 0; mt < 4; ++mt) {
        int r = 2 * wv + (mt >> 1), h = mt & 1;
        int pos = (r + dy) * 34 + h * 16 + m16 + dx;
        f16x8 ahi = *(const f16x8*)(s_in + swz(pos, q));
        f16x8 alo = *(const f16x8*)(s_in + 10880 + swz(pos, q));
#pragma unroll
        for (int nt = 0; nt < NFRAG; ++nt) {
          acc[mt][nt] = __builtin_amdgcn_mfma_f32_16x16x32_f16(
              ahi, blo[nt], acc[mt][nt], 0, 0, 0);
          acc[mt][nt] = __builtin_amdgcn_mfma_f32_16x16x32_f16(
              alo, bhi[nt], acc[mt][nt], 0, 0, 0);
          acc[mt][nt] = __builtin_amdgcn_mfma_f32_16x16x32_f16(
              ahi, bhi[nt], acc[mt][nt], 0, 0, 0);
        }
      }
    }
  }

  // ---- epilogue: D[m=q*4+i][n=m16];  x = x0 + h*16 + m, oc = oc0+nt*16+m16
  const int img_o = img_out0 + iz;
#pragma unroll
  for (int mt = 0; mt < 4; ++mt) {
    int r = 2 * wv + (mt >> 1), h = mt & 1;
    int y = y0 + r;
    int xb = x0 + h * 16 + q * 4;
#pragma unroll
    for (int nt = 0; nt < NFRAG; ++nt) {
      int oc = oc_blk0 + nt * 16 + m16;
      if (oc < Cout) {
        float bsv = bias[oc];
        long base = ((long)img_o * Cout + oc) * HWX + (long)y * WW + xb;
#pragma unroll
        for (int i = 0; i < 4; ++i) {
          float v = acc[mt][nt][i] + bsv;
          if (RELU) v = fmaxf(v, 0.f);
          if (ADD) v += res[base + i];
          out[base + i] = v;
        }
      }
    }
  }
}

// ---------------------------------------------------------------------------
// Fallback VALU conv (conv_first CIN=3 and recon Cout=3).
// ---------------------------------------------------------------------------
template<int CIN, int CK, int OCB, bool RELU, bool ADD>
__global__ __launch_bounds__(256) void conv3x3_k(
    const float* __restrict__ in, const float* __restrict__ wgt,
    const float* __restrict__ bias, const float* __restrict__ res,
    float* __restrict__ out, int Cout, int nslice, int img_in0, int img_out0)
{
  __shared__ __align__(16) float s_in[CK][34][34];
  __shared__ __align__(16) float s_w[CK * 9 * OCB];

  const int tid = threadIdx.x;
  const int tx = tid & 31;
  const int ty = tid >> 5;
  const int iz = blockIdx.z / nslice;
  const int slice = blockIdx.z % nslice;
  const int oc0 = slice * OCB;
  const int x0 = blockIdx.x * 32;
  const int y0 = blockIdx.y * 32;

  float acc[4][OCB];
#pragma unroll
  for (int r = 0; r < 4; ++r)
#pragma unroll
    for (int o = 0; o < OCB; ++o) acc[r][o] = 0.f;

  const float* inb = in + (long)(img_in0 + iz) * CIN * HWX;

  for (int c0 = 0; c0 < CIN; c0 += CK) {
    __syncthreads();
    for (int idx = tid; idx < CK * 34 * 34; idx += 256) {
      int c = idx / 1156;
      int rem = idx % 1156;
      int iy = rem / 34, ix = rem % 34;
      int gy = y0 + iy - 1, gx = x0 + ix - 1;
      float v = 0.f;
      if (gy >= 0 && gy < HH && gx >= 0 && gx < WW)
        v = inb[(long)(c0 + c) * HWX + gy * WW + gx];
      s_in[c][iy][ix] = v;
    }
    for (int idx = tid; idx < CK * 9 * OCB; idx += 256) {
      int oc = idx % OCB;
      int ck = idx / OCB;
      int c = ck / 9, k = ck % 9;
      int ocg = oc0 + oc;
      float v = 0.f;
      if (ocg < Cout) v = wgt[((long)ocg * CIN + c0 + c) * 9 + k];
      s_w[idx] = v;
    }
    __syncthreads();

    for (int c = 0; c < CK; ++c) {
#pragma unroll
      for (int k = 0; k < 9; ++k) {
        const int ky = k / 3, kx = k % 3;
        float v0 = s_in[c][ty + ky][tx + kx];
        float v1 = s_in[c][ty + 8 + ky][tx + kx];
        float v2 = s_in[c][ty + 16 + ky][tx + kx];
        float v3 = s_in[c][ty + 24 + ky][tx + kx];
        const float4* wp = (const float4*)&s_w[(c * 9 + k) * OCB];
#pragma unroll
        for (int o4 = 0; o4 < OCB / 4; ++o4) {
          float4 w4 = wp[o4];
          acc[0][o4 * 4 + 0] += v0 * w4.x; acc[0][o4 * 4 + 1] += v0 * w4.y;
          acc[0][o4 * 4 + 2] += v0 * w4.z; acc[0][o4 * 4 + 3] += v0 * w4.w;
          acc[1][o4 * 4 + 0] += v1 * w4.x; acc[1][o4 * 4 + 1] += v1 * w4.y;
          acc[1][o4 * 4 + 2] += v1 * w4.z; acc[1][o4 * 4 + 3] += v1 * w4.w;
          acc[2][o4 * 4 + 0] += v2 * w4.x; acc[2][o4 * 4 + 1] += v2 * w4.y;
          acc[2][o4 * 4 + 2] += v2 * w4.z; acc[2][o4 * 4 + 3] += v2 * w4.w;
          acc[3][o4 * 4 + 0] += v3 * w4.x; acc[3][o4 * 4 + 1] += v3 * w4.y;
          acc[3][o4 * 4 + 2] += v3 * w4.z; acc[3][o4 * 4 + 3] += v3 * w4.w;
        }
      }
    }
  }

#pragma unroll
  for (int o = 0; o < OCB; ++o) {
    int ocg = oc0 + o;
    if (ocg < Cout) {
      float b = bias ? bias[ocg] : 0.f;
      long base = ((long)(img_out0 + iz) * Cout + ocg) * HWX;
#pragma unroll
      for (int r = 0; r < 4; ++r) {
        int y = y0 + ty + 8 * r;
        float v = acc[r][o] + b;
        if (RELU) v = fmaxf(v, 0.f);
        long ia = base + (long)y * WW + x0 + tx;
        if (ADD) v += res[ia];
        out[ia] = v;
      }
    }
  }
}

// ---------------------------------------------------------------------------
__global__ __launch_bounds__(256) void regroup_k(
    const float* __restrict__ src, float* __restrict__ dst, int supp_mode)
{
  int idx = blockIdx.x * 256 + threadIdx.x;
  int c = idx & 7;
  int p = (idx >> 3) & 16383;
  int g = (idx >> 17) & 7;
  int img = idx >> 20;
  int simg = img;
  if (supp_mode) {
    int b = img >> 2, ns = img & 3;
    simg = b * 5 + (ns < 2 ? ns : ns + 1);
  }
  dst[idx] = src[((simg * 64 + g * 8 + c) * HWX) + p];
}

__device__ __forceinline__ void bilin8(const float* __restrict__ sg,
                                       float py, float px, float* sv)
{
  float y0f = floorf(py), x0f = floorf(px);
  float wy = py - y0f, wx = px - x0f;
  float y1f = y0f + 1.f, x1f = x0f + 1.f;
  float my0 = (y0f >= 0.f && y0f <= 127.f) ? 1.f : 0.f;
  float my1 = (y1f >= 0.f && y1f <= 127.f) ? 1.f : 0.f;
  float mx0 = (x0f >= 0.f && x0f <= 127.f) ? 1.f : 0.f;
  float mx1 = (x1f >= 0.f && x1f <= 127.f) ? 1.f : 0.f;
  int yi0 = (int)fminf(fmaxf(y0f, 0.f), 127.f);
  int yi1 = (int)fminf(fmaxf(y1f, 0.f), 127.f);
  int xi0 = (int)fminf(fmaxf(x0f, 0.f), 127.f);
  int xi1 = (int)fminf(fmaxf(x1f, 0.f), 127.f);
  float w00 = (1.f - wy) * (1.f - wx) * my0 * mx0;
  float w01 = (1.f - wy) * wx * my0 * mx1;
  float w10 = wy * (1.f - wx) * my1 * mx0;
  float w11 = wy * wx * my1 * mx1;
  const float4* p00 = (const float4*)(sg + ((long)yi0 * WW + xi0) * 8);
  const float4* p01 = (const float4*)(sg + ((long)yi0 * WW + xi1) * 8);
  const float4* p10 = (const float4*)(sg + ((long)yi1 * WW + xi0) * 8);
  const float4* p11 = (const float4*)(sg + ((long)yi1 * WW + xi1) * 8);
  float4 a00 = p00[0], b00 = p00[1];
  float4 a01 = p01[0], b01 = p01[1];
  float4 a10 = p10[0], b10 = p10[1];
  float4 a11 = p11[0], b11 = p11[1];
  sv[0] = w00 * a00.x + w01 * a01.x + w10 * a10.x + w11 * a11.x;
  sv[1] = w00 * a00.y + w01 * a01.y + w10 * a10.y + w11 * a11.y;
  sv[2] = w00 * a00.z + w01 * a01.z + w10 * a10.z + w11 * a11.z;
  sv[3] = w00 * a00.w + w01 * a01.w + w10 * a10.w + w11 * a11.w;
  sv[4] = w00 * b00.x + w01 * b01.x + w10 * b10.x + w11 * b11.x;
  sv[5] = w00 * b00.y + w01 * b01.y + w10 * b10.y + w11 * b11.y;
  sv[6] = w00 * b00.z + w01 * b01.z + w10 * b10.z + w11 * b11.z;
  sv[7] = w00 * b00.w + w01 * b01.w + w10 * b10.w + w11 * b11.w;
}

__global__ __launch_bounds__(256) void deform_k(
    const float* __restrict__ srcg, const float* __restrict__ off,
    const float* __restrict__ wgt, float* __restrict__ out, int img0)
{
  __shared__ __align__(16) float s_w[8 * 9 * 32];
  const int tid = threadIdx.x;
  const int tx = tid & 31, ty = tid >> 5;
  const int iz = blockIdx.z >> 1;
  const int slice = blockIdx.z & 1;
  const int oc0 = slice * 32;
  const int img = img0 + iz;
  const int x = blockIdx.x * 32 + tx;
  const int ya = blockIdx.y * 16 + ty;
  const int yb = ya + 8;

  float acc0[32], acc1[32];
#pragma unroll
  for (int o = 0; o < 32; ++o) { acc0[o] = 0.f; acc1[o] = 0.f; }

  for (int g = 0; g < 8; ++g) {
    __syncthreads();
    for (int idx = tid; idx < 8 * 9 * 32; idx += 256) {
      int oc = idx & 31;
      int ck = idx >> 5;
      int cpg = ck / 9, k = ck % 9;
      s_w[idx] = wgt[((long)(oc0 + oc) * 64 + g * 8 + cpg) * 9 + k];
    }
    __syncthreads();

    const float* offp = off + ((long)iz * 144 + g * 18) * HWX + x;
    const float* sg = srcg + (long)(img * 8 + g) * HWX * 8;

#pragma unroll 1
    for (int k = 0; k < 9; ++k) {
      float dy0 = offp[(2 * k) * HWX + ya * WW];
      float dx0 = offp[(2 * k + 1) * HWX + ya * WW];
      float dy1 = offp[(2 * k) * HWX + yb * WW];
      float dx1 = offp[(2 * k + 1) * HWX + yb * WW];
      float kyf = (float)(k / 3 - 1), kxf = (float)(k % 3 - 1);
      float sv0[8], sv1[8];
      bilin8(sg, dy0 + (float)ya + kyf, dx0 + (float)x + kxf, sv0);
      bilin8(sg, dy1 + (float)yb + kyf, dx1 + (float)x + kxf, sv1);
#pragma unroll
      for (int cpg = 0; cpg < 8; ++cpg) {
        float u0 = sv0[cpg], u1 = sv1[cpg];
        const float4* wp = (const float4*)&s_w[(cpg * 9 + k) * 32];
#pragma unroll
        for (int o4 = 0; o4 < 8; ++o4) {
          float4 w4 = wp[o4];
          acc0[o4 * 4 + 0] += u0 * w4.x; acc1[o4 * 4 + 0] += u1 * w4.x;
          acc0[o4 * 4 + 1] += u0 * w4.y; acc1[o4 * 4 + 1] += u1 * w4.y;
          acc0[o4 * 4 + 2] += u0 * w4.z; acc1[o4 * 4 + 2] += u1 * w4.z;
          acc0[o4 * 4 + 3] += u0 * w4.w; acc1[o4 * 4 + 3] += u1 * w4.w;
        }
      }
    }
  }

  long obase = ((long)img * 64 + oc0) * HWX + x;
#pragma unroll
  for (int o = 0; o < 32; ++o) {
    out[obase + (long)o * HWX + (long)ya * WW] = acc0[o];
    out[obase + (long)o * HWX + (long)yb * WW] = acc1[o];
  }
}

__global__ __launch_bounds__(256) void assemble_k(
    const float* __restrict__ x, const float* __restrict__ im,
    const float* __restrict__ out0, const float* __restrict__ fea,
    float* __restrict__ out)
{
  int idx = blockIdx.x * 256 + threadIdx.x;
  if (idx < 491520) {
    int within = idx % 49152;
    int n = (idx / 49152) % 5;
    int b = idx / (49152 * 5);
    float v;
    if (n == 2) v = x[(b * 5 + 2) * 49152 + within];
    else {
      int j = b * 4 + (n < 2 ? n : n - 1);
      v = im[j * 49152 + within];
    }
    out[idx] = v;
  } else if (idx < 10977280) {
    int idx2 = idx - 491520;
    int within = idx2 % 1048576;
    int n = (idx2 / 1048576) % 5;
    int b = idx2 / (1048576 * 5);
    float v;
    if (n == 2) v = out0[(b * 5 + 2) * 1048576 + within];
    else {
      int j = b * 4 + (n < 2 ? n : n - 1);
      v = fea[j * 1048576 + within];
    }
    out[idx] = v;
  }
}

// ---------------------------------------------------------------------------
extern "C" void kernel_launch(void* const* d_in, const int* in_sizes, int n_in,
                              void* d_out, int out_size, void* d_ws, size_t ws_size,
                              hipStream_t stream) {
  const float* x   = (const float*)d_in[0];
  const float* cfw = (const float*)d_in[1];
  const float* cfb = (const float*)d_in[2];
  const float* rw1 = (const float*)d_in[3];
  const float* rb1 = (const float*)d_in[4];
  const float* rw2 = (const float*)d_in[5];
  const float* rb2 = (const float*)d_in[6];
  const float* crw = (const float*)d_in[7];
  const float* crb = (const float*)d_in[8];
  const float* ofw = (const float*)d_in[9];
  const float* ofb = (const float*)d_in[10];
  const float* dcw = (const float*)d_in[11];
  const float* rcw = (const float*)d_in[12];
  const float* rcb = (const float*)d_in[13];
  float* out = (float*)d_out;

  // split-fp16 weight arenas: [res1 x5 | res2 x5 | cr | off x4] = 774144 each
  unsigned short* WH = (unsigned short*)d_ws;
  unsigned short* WL = WH + 774144;
  const long W_res1 = 0, W_res2 = 184320, W_cr = 368640, W_off = 442368;

  float* A = (float*)d_ws + 786432;                  // (10,64,HW)
  float* C = A + 10485760;                           // fea ping (8,64,HW)
  float* D = C + 8388608;                            // grouped / im
  float* F = D + 8388608;                            // fea3
  float* OFF = F + 8388608;                          // offsets (chunk,144,HW)
  float* r = C;
  float* im = D;

  const size_t fixedF = 786432UL + 10485760UL + 3UL * 8388608UL;
  int chunk = 8;
  while (chunk > 1 && (fixedF + (size_t)chunk * 2359296UL) * sizeof(float) > ws_size)
    chunk >>= 1;

  dim3 blk(256);

  // weight prep (split fp16)
  wprep_k<<<720, blk, 0, stream>>>(rw1, WH + W_res1, WL + W_res1, 64, 64, 5);
  wprep_k<<<720, blk, 0, stream>>>(rw2, WH + W_res2, WL + W_res2, 64, 64, 5);
  wprep_k<<<288, blk, 0, stream>>>(crw, WH + W_cr, WL + W_cr, 64, 128, 1);
  wprep_k<<<1296, blk, 0, stream>>>(ofw, WH + W_off, WL + W_off, 144, 64, 4);

  // conv_first + ReLU : x (10,3,HW) -> A (10,64,HW)   [VALU fp32, CIN=3]
  conv3x3_k<3, 3, 16, true, false><<<dim3(4, 4, 40), blk, 0, stream>>>(
      x, cfw, cfb, nullptr, A, 64, 4, 0, 0);

  // 5 residual blocks (split-fp16 MFMA)
  for (int i = 0; i < 5; ++i) {
    conv_mfma_k<2, 2, true, false, false><<<dim3(4, 16, 20), blk, 0, stream>>>(
        A, WH + W_res1 + (long)i * 36864, WL + W_res1 + (long)i * 36864,
        rb1 + i * 64, nullptr, r, 64, 2, 0, 0);
    conv_mfma_k<2, 2, false, true, false><<<dim3(4, 16, 20), blk, 0, stream>>>(
        r, WH + W_res2 + (long)i * 36864, WL + W_res2 + (long)i * 36864,
        rb2 + i * 64, A, A, 64, 2, 0, 0);
  }

  // cr conv, fused concat(ref,supp): A -> C (fea0)
  conv_mfma_k<4, 2, false, false, true><<<dim3(4, 16, 16), blk, 0, stream>>>(
      A, WH + W_cr, WL + W_cr, crb, nullptr, C, 64, 2, 0, 0);

  // offset conv (split-fp16 MFMA, 144ch = 3x48) + deform, chunked over imgs
  auto off_deform = [&](const float* fea_in, const float* grouped,
                        int layer, float* outp) {
    for (int i0 = 0; i0 < 8; i0 += chunk) {
      conv_mfma_k<2, 3, false, false, false>
          <<<dim3(4, 16, chunk * 3), blk, 0, stream>>>(
              fea_in, WH + W_off + (long)layer * 82944,
              WL + W_off + (long)layer * 82944, ofb + layer * 144,
              nullptr, OFF, 144, 3, i0, 0);
      deform_k<<<dim3(4, 8, chunk * 2), blk, 0, stream>>>(
          grouped, OFF, dcw + (long)layer * 36864, outp, i0);
    }
  };

  // layer 0: fea1 = deform(fea0, conv(fea0))        C -> C
  regroup_k<<<32768, blk, 0, stream>>>(C, D, 0);
  off_deform(C, D, 0, C);

  // layer 1: fea2 = deform(fea1, conv(fea1))        C -> C
  regroup_k<<<32768, blk, 0, stream>>>(C, D, 0);
  off_deform(C, D, 1, C);

  // layer 2: fea3 = deform(supp, conv(fea2))        (A supp, C) -> F
  regroup_k<<<32768, blk, 0, stream>>>(A, D, 1);
  off_deform(C, D, 2, F);

  // layer 3: aligned = deform(fea3, conv(fea3))     F -> C
  regroup_k<<<32768, blk, 0, stream>>>(F, D, 0);
  off_deform(F, D, 3, C);

  // recon conv: aligned -> im (8,3,HW)   [VALU fp32, Cout=3]
  conv3x3_k<64, 8, 4, false, false><<<dim3(4, 4, 8), blk, 0, stream>>>(
      C, rcw, rcb, nullptr, im, 3, 1, 0, 0);

  // assemble outputs
  assemble_k<<<42880, blk, 0, stream>>>(x, im, A, F, out);
}

// Round 5
// 2495.608 us; speedup vs baseline: 2.2418x; 1.1280x over previous
//
#include <hip/hip_runtime.h>

#define HH 128
#define WW 128
#define HWX (HH*WW)

using f32x4 = __attribute__((ext_vector_type(4))) float;
using f16x8 = __attribute__((ext_vector_type(8))) _Float16;

__device__ __forceinline__ unsigned short f16bits(_Float16 h) {
  union { _Float16 f; unsigned short u; } v; v.f = h; return v.u;
}

// chunk swizzle: position pos (64B row of 32 f16), chunk q (16B of 8 f16)
__device__ __forceinline__ int swz(int pos, int q) {
  return pos * 32 + (((q + pos + (pos >> 2)) & 3) << 3);
}

// ---------------------------------------------------------------------------
// Weight prep: OIHW fp32 -> [layer][kpos][O][I] split-fp16 (hi + lo arenas)
// ---------------------------------------------------------------------------
__global__ __launch_bounds__(256) void wprep_k(
    const float* __restrict__ src, unsigned short* __restrict__ dhi,
    unsigned short* __restrict__ dlo, int O, int I, int L)
{
  int idx = blockIdx.x * 256 + threadIdx.x;
  int tot = L * O * I * 9;
  if (idx >= tot) return;
  int per = O * I * 9;
  int layer = idx / per;
  int r = idx - layer * per;
  int o = r / (I * 9);
  int r2 = r - o * (I * 9);
  int i = r2 / 9, k = r2 - i * 9;
  float v = src[idx];
  _Float16 h = (_Float16)v;
  _Float16 l = (_Float16)(v - (float)h);
  long di = (long)layer * per + ((long)k * O + o) * I + i;
  dhi[di] = f16bits(h);
  dlo[di] = f16bits(l);
}

// ---------------------------------------------------------------------------
// Deform weight prep: [L][O=64][I=64][9] fp32 -> [L][k2][o][r=I] split-fp16
// ---------------------------------------------------------------------------
__global__ __launch_bounds__(256) void dwprep_k(
    const float* __restrict__ src, unsigned short* __restrict__ dhi,
    unsigned short* __restrict__ dlo)
{
  int idx = blockIdx.x * 256 + threadIdx.x;      // 4*36864 = 147456
  if (idx >= 147456) return;
  int l = idx / 36864;
  int rem = idx - l * 36864;
  int o = rem / 576;
  int rem2 = rem - o * 576;
  int r = rem2 / 9, k2 = rem2 - r * 9;
  float v = src[idx];
  _Float16 h = (_Float16)v;
  _Float16 lo = (_Float16)(v - (float)h);
  long di = (((long)l * 9 + k2) * 64 + o) * 64 + r;
  dhi[di] = f16bits(h);
  dlo[di] = f16bits(lo);
}

// ---------------------------------------------------------------------------
// Split-fp16 MFMA implicit-GEMM 3x3 SAME conv. Block 256 thr = 4 waves.
// ---------------------------------------------------------------------------
template<int CBLK, int NFRAG, bool RELU, bool ADD, bool CRMODE>
__global__ __launch_bounds__(256, 2) void conv_mfma_k(
    const float* __restrict__ in, const unsigned short* __restrict__ whi,
    const unsigned short* __restrict__ wlo,
    const float* __restrict__ bias, const float* __restrict__ res,
    float* __restrict__ out, int Cout, int nslice, int img_in0, int img_out0)
{
  constexpr int CIN = CBLK * 32;
  constexpr int OCB = NFRAG * 16;
  constexpr int WHALF = 9 * OCB * 32;
  __shared__ __align__(16) unsigned short s_in[2 * 10880];   // 10x34 halo, hi|lo
  __shared__ __align__(16) unsigned short s_w[2 * WHALF];    // hi|lo

  const int tid = threadIdx.x;
  const int lane = tid & 63;
  const int wv = tid >> 6;
  const int m16 = lane & 15, q = lane >> 4;
  const int iz = blockIdx.z / nslice, slice = blockIdx.z % nslice;
  const int oc_blk0 = slice * OCB;
  const int x0 = blockIdx.x * 32, y0 = blockIdx.y * 8;

  f32x4 acc[4][NFRAG];
#pragma unroll
  for (int mt = 0; mt < 4; ++mt)
#pragma unroll
    for (int nt = 0; nt < NFRAG; ++nt)
#pragma unroll
      for (int i = 0; i < 4; ++i) acc[mt][nt][i] = 0.f;

  int bb = 0, nn = 0;
  const float* inb = in;
  if (CRMODE) {
    int j = img_in0 + iz;
    bb = j >> 2;
    int ns = j & 3;
    nn = ns < 2 ? ns : ns + 1;
  } else {
    inb = in + (long)(img_in0 + iz) * CIN * HWX;
  }

  for (int cb = 0; cb < CBLK; ++cb) {
    const int c0 = cb * 32;
    __syncthreads();
    for (int t = tid; t < 1360; t += 256) {
      int qq = t / 340, pos = t - qq * 340;
      int iy = pos / 34, ix = pos - iy * 34;
      int gy = y0 + iy - 1, gx = x0 + ix - 1;
      bool inr = (gy >= 0 && gy < HH && gx >= 0 && gx < WW);
      const float* src;
      if (CRMODE) {
        int ch = c0 + qq * 8;
        int simg = (ch < 64) ? (bb * 5 + 2) : (bb * 5 + nn);
        src = in + ((long)simg * 64 + (ch & 63)) * HWX + gy * WW + gx;
      } else {
        src = inb + (long)(c0 + qq * 8) * HWX + gy * WW + gx;
      }
      unsigned hi4[4], lo4[4];
#pragma unroll
      for (int j2 = 0; j2 < 4; ++j2) {
        unsigned short hs[2], ls[2];
#pragma unroll
        for (int j = 0; j < 2; ++j) {
          float v = inr ? src[(long)(j2 * 2 + j) * HWX] : 0.f;
          _Float16 h = (_Float16)v;
          _Float16 l = (_Float16)(v - (float)h);
          hs[j] = f16bits(h); ls[j] = f16bits(l);
        }
        hi4[j2] = (unsigned)hs[0] | ((unsigned)hs[1] << 16);
        lo4[j2] = (unsigned)ls[0] | ((unsigned)ls[1] << 16);
      }
      *(uint4*)(s_in + swz(pos, qq)) = make_uint4(hi4[0], hi4[1], hi4[2], hi4[3]);
      *(uint4*)(s_in + 10880 + swz(pos, qq)) =
          make_uint4(lo4[0], lo4[1], lo4[2], lo4[3]);
    }
    for (int t = tid; t < 9 * OCB * 4; t += 256) {
      int qq = t / (9 * OCB), pw = t - qq * (9 * OCB);
      int kp = pw / OCB, ocl = pw - kp * OCB;
      long so = ((long)kp * Cout + oc_blk0 + ocl) * CIN + c0 + qq * 8;
      *(uint4*)(s_w + swz(pw, qq)) = *(const uint4*)(whi + so);
      *(uint4*)(s_w + WHALF + swz(pw, qq)) = *(const uint4*)(wlo + so);
    }
    __syncthreads();

#pragma unroll
    for (int kp = 0; kp < 9; ++kp) {
      const int dy = kp / 3, dx = kp - dy * 3;
      f16x8 bhi[NFRAG], blo[NFRAG];
#pragma unroll
      for (int nt = 0; nt < NFRAG; ++nt) {
        int pw = kp * OCB + nt * 16 + m16;
        bhi[nt] = *(const f16x8*)(s_w + swz(pw, q));
        blo[nt] = *(const f16x8*)(s_w + WHALF + swz(pw, q));
      }
#pragma unroll
      for (int mt = 0; mt < 4; ++mt) {
        int r = 2 * wv + (mt >> 1), h = mt & 1;
        int pos = (r + dy) * 34 + h * 16 + m16 + dx;
        f16x8 ahi = *(const f16x8*)(s_in + swz(pos, q));
        f16x8 alo = *(const f16x8*)(s_in + 10880 + swz(pos, q));
#pragma unroll
        for (int nt = 0; nt < NFRAG; ++nt) {
          acc[mt][nt] = __builtin_amdgcn_mfma_f32_16x16x32_f16(
              ahi, blo[nt], acc[mt][nt], 0, 0, 0);
          acc[mt][nt] = __builtin_amdgcn_mfma_f32_16x16x32_f16(
              alo, bhi[nt], acc[mt][nt], 0, 0, 0);
          acc[mt][nt] = __builtin_amdgcn_mfma_f32_16x16x32_f16(
              ahi, bhi[nt], acc[mt][nt], 0, 0, 0);
        }
      }
    }
  }

  const int img_o = img_out0 + iz;
#pragma unroll
  for (int mt = 0; mt < 4; ++mt) {
    int r = 2 * wv + (mt >> 1), h = mt & 1;
    int y = y0 + r;
    int xb = x0 + h * 16 + q * 4;
#pragma unroll
    for (int nt = 0; nt < NFRAG; ++nt) {
      int oc = oc_blk0 + nt * 16 + m16;
      if (oc < Cout) {
        float bsv = bias[oc];
        long base = ((long)img_o * Cout + oc) * HWX + (long)y * WW + xb;
#pragma unroll
        for (int i = 0; i < 4; ++i) {
          float v = acc[mt][nt][i] + bsv;
          if (RELU) v = fmaxf(v, 0.f);
          if (ADD) v += res[base + i];
          out[base + i] = v;
        }
      }
    }
  }
}

// ---------------------------------------------------------------------------
// Fallback VALU conv (conv_first CIN=3 and recon Cout=3).
// ---------------------------------------------------------------------------
template<int CIN, int CK, int OCB, bool RELU, bool ADD>
__global__ __launch_bounds__(256) void conv3x3_k(
    const float* __restrict__ in, const float* __restrict__ wgt,
    const float* __restrict__ bias, const float* __restrict__ res,
    float* __restrict__ out, int Cout, int nslice, int img_in0, int img_out0)
{
  __shared__ __align__(16) float s_in[CK][34][34];
  __shared__ __align__(16) float s_w[CK * 9 * OCB];

  const int tid = threadIdx.x;
  const int tx = tid & 31;
  const int ty = tid >> 5;
  const int iz = blockIdx.z / nslice;
  const int slice = blockIdx.z % nslice;
  const int oc0 = slice * OCB;
  const int x0 = blockIdx.x * 32;
  const int y0 = blockIdx.y * 32;

  float acc[4][OCB];
#pragma unroll
  for (int r = 0; r < 4; ++r)
#pragma unroll
    for (int o = 0; o < OCB; ++o) acc[r][o] = 0.f;

  const float* inb = in + (long)(img_in0 + iz) * CIN * HWX;

  for (int c0 = 0; c0 < CIN; c0 += CK) {
    __syncthreads();
    for (int idx = tid; idx < CK * 34 * 34; idx += 256) {
      int c = idx / 1156;
      int rem = idx % 1156;
      int iy = rem / 34, ix = rem % 34;
      int gy = y0 + iy - 1, gx = x0 + ix - 1;
      float v = 0.f;
      if (gy >= 0 && gy < HH && gx >= 0 && gx < WW)
        v = inb[(long)(c0 + c) * HWX + gy * WW + gx];
      s_in[c][iy][ix] = v;
    }
    for (int idx = tid; idx < CK * 9 * OCB; idx += 256) {
      int oc = idx % OCB;
      int ck = idx / OCB;
      int c = ck / 9, k = ck % 9;
      int ocg = oc0 + oc;
      float v = 0.f;
      if (ocg < Cout) v = wgt[((long)ocg * CIN + c0 + c) * 9 + k];
      s_w[idx] = v;
    }
    __syncthreads();

    for (int c = 0; c < CK; ++c) {
#pragma unroll
      for (int k = 0; k < 9; ++k) {
        const int ky = k / 3, kx = k % 3;
        float v0 = s_in[c][ty + ky][tx + kx];
        float v1 = s_in[c][ty + 8 + ky][tx + kx];
        float v2 = s_in[c][ty + 16 + ky][tx + kx];
        float v3 = s_in[c][ty + 24 + ky][tx + kx];
        const float4* wp = (const float4*)&s_w[(c * 9 + k) * OCB];
#pragma unroll
        for (int o4 = 0; o4 < OCB / 4; ++o4) {
          float4 w4 = wp[o4];
          acc[0][o4 * 4 + 0] += v0 * w4.x; acc[0][o4 * 4 + 1] += v0 * w4.y;
          acc[0][o4 * 4 + 2] += v0 * w4.z; acc[0][o4 * 4 + 3] += v0 * w4.w;
          acc[1][o4 * 4 + 0] += v1 * w4.x; acc[1][o4 * 4 + 1] += v1 * w4.y;
          acc[1][o4 * 4 + 2] += v1 * w4.z; acc[1][o4 * 4 + 3] += v1 * w4.w;
          acc[2][o4 * 4 + 0] += v2 * w4.x; acc[2][o4 * 4 + 1] += v2 * w4.y;
          acc[2][o4 * 4 + 2] += v2 * w4.z; acc[2][o4 * 4 + 3] += v2 * w4.w;
          acc[3][o4 * 4 + 0] += v3 * w4.x; acc[3][o4 * 4 + 1] += v3 * w4.y;
          acc[3][o4 * 4 + 2] += v3 * w4.z; acc[3][o4 * 4 + 3] += v3 * w4.w;
        }
      }
    }
  }

#pragma unroll
  for (int o = 0; o < OCB; ++o) {
    int ocg = oc0 + o;
    if (ocg < Cout) {
      float b = bias ? bias[ocg] : 0.f;
      long base = ((long)(img_out0 + iz) * Cout + ocg) * HWX;
#pragma unroll
      for (int r = 0; r < 4; ++r) {
        int y = y0 + ty + 8 * r;
        float v = acc[r][o] + b;
        if (RELU) v = fmaxf(v, 0.f);
        long ia = base + (long)y * WW + x0 + tx;
        if (ADD) v += res[ia];
        out[ia] = v;
      }
    }
  }
}

// ---------------------------------------------------------------------------
__global__ __launch_bounds__(256) void regroup_k(
    const float* __restrict__ src, float* __restrict__ dst, int supp_mode)
{
  int idx = blockIdx.x * 256 + threadIdx.x;
  int c = idx & 7;
  int p = (idx >> 3) & 16383;
  int g = (idx >> 17) & 7;
  int img = idx >> 20;
  int simg = img;
  if (supp_mode) {
    int b = img >> 2, ns = img & 3;
    simg = b * 5 + (ns < 2 ? ns : ns + 1);
  }
  dst[idx] = src[((simg * 64 + g * 8 + c) * HWX) + p];
}

__device__ __forceinline__ void bilin8(const float* __restrict__ sg,
                                       float py, float px, float* sv)
{
  float y0f = floorf(py), x0f = floorf(px);
  float wy = py - y0f, wx = px - x0f;
  float y1f = y0f + 1.f, x1f = x0f + 1.f;
  float my0 = (y0f >= 0.f && y0f <= 127.f) ? 1.f : 0.f;
  float my1 = (y1f >= 0.f && y1f <= 127.f) ? 1.f : 0.f;
  float mx0 = (x0f >= 0.f && x0f <= 127.f) ? 1.f : 0.f;
  float mx1 = (x1f >= 0.f && x1f <= 127.f) ? 1.f : 0.f;
  int yi0 = (int)fminf(fmaxf(y0f, 0.f), 127.f);
  int yi1 = (int)fminf(fmaxf(y1f, 0.f), 127.f);
  int xi0 = (int)fminf(fmaxf(x0f, 0.f), 127.f);
  int xi1 = (int)fminf(fmaxf(x1f, 0.f), 127.f);
  float w00 = (1.f - wy) * (1.f - wx) * my0 * mx0;
  float w01 = (1.f - wy) * wx * my0 * mx1;
  float w10 = wy * (1.f - wx) * my1 * mx0;
  float w11 = wy * wx * my1 * mx1;
  const float4* p00 = (const float4*)(sg + ((long)yi0 * WW + xi0) * 8);
  const float4* p01 = (const float4*)(sg + ((long)yi0 * WW + xi1) * 8);
  const float4* p10 = (const float4*)(sg + ((long)yi1 * WW + xi0) * 8);
  const float4* p11 = (const float4*)(sg + ((long)yi1 * WW + xi1) * 8);
  float4 a00 = p00[0], b00 = p00[1];
  float4 a01 = p01[0], b01 = p01[1];
  float4 a10 = p10[0], b10 = p10[1];
  float4 a11 = p11[0], b11 = p11[1];
  sv[0] = w00 * a00.x + w01 * a01.x + w10 * a10.x + w11 * a11.x;
  sv[1] = w00 * a00.y + w01 * a01.y + w10 * a10.y + w11 * a11.y;
  sv[2] = w00 * a00.z + w01 * a01.z + w10 * a10.z + w11 * a11.z;
  sv[3] = w00 * a00.w + w01 * a01.w + w10 * a10.w + w11 * a11.w;
  sv[4] = w00 * b00.x + w01 * b01.x + w10 * b10.x + w11 * b11.x;
  sv[5] = w00 * b00.y + w01 * b01.y + w10 * b10.y + w11 * b11.y;
  sv[6] = w00 * b00.z + w01 * b01.z + w10 * b10.z + w11 * b11.z;
  sv[7] = w00 * b00.w + w01 * b01.w + w10 * b10.w + w11 * b11.w;
}

// ---------------------------------------------------------------------------
// Deform as split-fp16 MFMA implicit GEMM with fused bilinear sampling.
// M = pixels (wave: 16 px), N = 64 oc (4 frags), K = 576 = (k2,g,cpg).
// Per k2: stage 64x64 weight slab (hi+lo) in LDS with 8-elem rotation swizzle.
// Lane (m16,q): A-frag for K-step s = bilin8 sample at (px=m16 tile px,
// g=4s+q, k2), split hi/lo. grid = (256 px-blocks, img chunk).
// ---------------------------------------------------------------------------
__global__ __launch_bounds__(256) void deform_mfma_k(
    const float* __restrict__ srcg, const float* __restrict__ off,
    const unsigned short* __restrict__ wh, const unsigned short* __restrict__ wl,
    float* __restrict__ out, int img0)
{
  __shared__ __align__(16) unsigned short s_bh[4096];
  __shared__ __align__(16) unsigned short s_bl[4096];
  const int tid = threadIdx.x;
  const int lane = tid & 63;
  const int wv = tid >> 6;
  const int m16 = lane & 15, q = lane >> 4;
  const int iz = blockIdx.y;
  const int img = img0 + iz;
  const int tile_p = blockIdx.x * 64 + wv * 16;
  const int p = tile_p + m16;
  const float fy = (float)(p >> 7), fx = (float)(p & 127);
  const int rot = 8 * (m16 & 7);

  f32x4 acc[4];
#pragma unroll
  for (int nt = 0; nt < 4; ++nt)
#pragma unroll
    for (int i = 0; i < 4; ++i) acc[nt][i] = 0.f;

  for (int k2 = 0; k2 < 9; ++k2) {
    __syncthreads();
    // stage weight slab [o=64][r=64] hi+lo, rotated by o within 64-f16 rows
    for (int t = tid; t < 512; t += 256) {
      int o = t >> 3, j = t & 7;
      int d = o * 64 + ((8 * j + 8 * (o & 7)) & 63);
      long so = ((long)k2 * 64 + o) * 64 + 8 * j;
      *(uint4*)(s_bh + d) = *(const uint4*)(wh + so);
      *(uint4*)(s_bl + d) = *(const uint4*)(wl + so);
    }
    __syncthreads();
    const float kyf = (float)(k2 / 3 - 1), kxf = (float)(k2 % 3 - 1);
#pragma unroll
    for (int s = 0; s < 2; ++s) {
      const int g = 4 * s + q;
      const float* offp = off + ((long)iz * 144 + g * 18 + 2 * k2) * HWX + p;
      float dyv = offp[0], dxv = offp[HWX];
      float sv[8];
      bilin8(srcg + (long)(img * 8 + g) * HWX * 8,
             dyv + fy + kyf, dxv + fx + kxf, sv);
      f16x8 ah, al;
#pragma unroll
      for (int j = 0; j < 8; ++j) {
        _Float16 h = (_Float16)sv[j];
        _Float16 l = (_Float16)(sv[j] - (float)h);
        ah[j] = h; al[j] = l;
      }
      const int roff = (32 * s + 8 * q + rot) & 63;
#pragma unroll
      for (int nt = 0; nt < 4; ++nt) {
        int o = nt * 16 + m16;
        f16x8 bh = *(const f16x8*)(s_bh + o * 64 + roff);
        f16x8 bl = *(const f16x8*)(s_bl + o * 64 + roff);
        acc[nt] = __builtin_amdgcn_mfma_f32_16x16x32_f16(ah, bl, acc[nt], 0, 0, 0);
        acc[nt] = __builtin_amdgcn_mfma_f32_16x16x32_f16(al, bh, acc[nt], 0, 0, 0);
        acc[nt] = __builtin_amdgcn_mfma_f32_16x16x32_f16(ah, bh, acc[nt], 0, 0, 0);
      }
    }
  }

  const long pb = tile_p + q * 4;
#pragma unroll
  for (int nt = 0; nt < 4; ++nt) {
    int oc = nt * 16 + m16;
    float4 v;
    v.x = acc[nt][0]; v.y = acc[nt][1]; v.z = acc[nt][2]; v.w = acc[nt][3];
    *(float4*)(out + ((long)img * 64 + oc) * HWX + pb) = v;
  }
}

__global__ __launch_bounds__(256) void assemble_k(
    const float* __restrict__ x, const float* __restrict__ im,
    const float* __restrict__ out0, const float* __restrict__ fea,
    float* __restrict__ out)
{
  int idx = blockIdx.x * 256 + threadIdx.x;
  if (idx < 491520) {
    int within = idx % 49152;
    int n = (idx / 49152) % 5;
    int b = idx / (49152 * 5);
    float v;
    if (n == 2) v = x[(b * 5 + 2) * 49152 + within];
    else {
      int j = b * 4 + (n < 2 ? n : n - 1);
      v = im[j * 49152 + within];
    }
    out[idx] = v;
  } else if (idx < 10977280) {
    int idx2 = idx - 491520;
    int within = idx2 % 1048576;
    int n = (idx2 / 1048576) % 5;
    int b = idx2 / (1048576 * 5);
    float v;
    if (n == 2) v = out0[(b * 5 + 2) * 1048576 + within];
    else {
      int j = b * 4 + (n < 2 ? n : n - 1);
      v = fea[j * 1048576 + within];
    }
    out[idx] = v;
  }
}

// ---------------------------------------------------------------------------
extern "C" void kernel_launch(void* const* d_in, const int* in_sizes, int n_in,
                              void* d_out, int out_size, void* d_ws, size_t ws_size,
                              hipStream_t stream) {
  const float* x   = (const float*)d_in[0];
  const float* cfw = (const float*)d_in[1];
  const float* cfb = (const float*)d_in[2];
  const float* rw1 = (const float*)d_in[3];
  const float* rb1 = (const float*)d_in[4];
  const float* rw2 = (const float*)d_in[5];
  const float* rb2 = (const float*)d_in[6];
  const float* crw = (const float*)d_in[7];
  const float* crb = (const float*)d_in[8];
  const float* ofw = (const float*)d_in[9];
  const float* ofb = (const float*)d_in[10];
  const float* dcw = (const float*)d_in[11];
  const float* rcw = (const float*)d_in[12];
  const float* rcb = (const float*)d_in[13];
  float* out = (float*)d_out;

  // conv weight arenas (hi|lo), then deform weight arenas (hi|lo)
  unsigned short* WH = (unsigned short*)d_ws;
  unsigned short* WL = WH + 774144;
  unsigned short* DH = WH + 1548288;
  unsigned short* DL = DH + 147456;
  const long W_res1 = 0, W_res2 = 184320, W_cr = 368640, W_off = 442368;

  float* A = (float*)d_ws + 921600;                  // (10,64,HW)
  float* C = A + 10485760;                           // fea ping (8,64,HW)
  float* D = C + 8388608;                            // grouped / im
  float* F = D + 8388608;                            // fea3
  float* OFF = F + 8388608;                          // offsets (chunk,144,HW)
  float* r = C;
  float* im = D;

  const size_t fixedF = 921600UL + 10485760UL + 3UL * 8388608UL;
  int chunk = 8;
  while (chunk > 1 && (fixedF + (size_t)chunk * 2359296UL) * sizeof(float) > ws_size)
    chunk >>= 1;

  dim3 blk(256);

  // weight prep
  wprep_k<<<720, blk, 0, stream>>>(rw1, WH + W_res1, WL + W_res1, 64, 64, 5);
  wprep_k<<<720, blk, 0, stream>>>(rw2, WH + W_res2, WL + W_res2, 64, 64, 5);
  wprep_k<<<288, blk, 0, stream>>>(crw, WH + W_cr, WL + W_cr, 64, 128, 1);
  wprep_k<<<1296, blk, 0, stream>>>(ofw, WH + W_off, WL + W_off, 144, 64, 4);
  dwprep_k<<<576, blk, 0, stream>>>(dcw, DH, DL);

  // conv_first + ReLU : x (10,3,HW) -> A (10,64,HW)   [VALU fp32, CIN=3]
  conv3x3_k<3, 3, 16, true, false><<<dim3(4, 4, 40), blk, 0, stream>>>(
      x, cfw, cfb, nullptr, A, 64, 4, 0, 0);

  // 5 residual blocks (split-fp16 MFMA)
  for (int i = 0; i < 5; ++i) {
    conv_mfma_k<2, 2, true, false, false><<<dim3(4, 16, 20), blk, 0, stream>>>(
        A, WH + W_res1 + (long)i * 36864, WL + W_res1 + (long)i * 36864,
        rb1 + i * 64, nullptr, r, 64, 2, 0, 0);
    conv_mfma_k<2, 2, false, true, false><<<dim3(4, 16, 20), blk, 0, stream>>>(
        r, WH + W_res2 + (long)i * 36864, WL + W_res2 + (long)i * 36864,
        rb2 + i * 64, A, A, 64, 2, 0, 0);
  }

  // cr conv, fused concat(ref,supp): A -> C (fea0)
  conv_mfma_k<4, 2, false, false, true><<<dim3(4, 16, 16), blk, 0, stream>>>(
      A, WH + W_cr, WL + W_cr, crb, nullptr, C, 64, 2, 0, 0);

  // offset conv (split-fp16 MFMA, 144ch = 3x48) + deform (MFMA), chunked
  auto off_deform = [&](const float* fea_in, const float* grouped,
                        int layer, float* outp) {
    for (int i0 = 0; i0 < 8; i0 += chunk) {
      conv_mfma_k<2, 3, false, false, false>
          <<<dim3(4, 16, chunk * 3), blk, 0, stream>>>(
              fea_in, WH + W_off + (long)layer * 82944,
              WL + W_off + (long)layer * 82944, ofb + layer * 144,
              nullptr, OFF, 144, 3, i0, 0);
      deform_mfma_k<<<dim3(256, chunk), blk, 0, stream>>>(
          grouped, OFF, DH + (long)layer * 36864, DL + (long)layer * 36864,
          outp, i0);
    }
  };

  // layer 0: fea1 = deform(fea0, conv(fea0))        C -> C
  regroup_k<<<32768, blk, 0, stream>>>(C, D, 0);
  off_deform(C, D, 0, C);

  // layer 1: fea2 = deform(fea1, conv(fea1))        C -> C
  regroup_k<<<32768, blk, 0, stream>>>(C, D, 0);
  off_deform(C, D, 1, C);

  // layer 2: fea3 = deform(supp, conv(fea2))        (A supp, C) -> F
  regroup_k<<<32768, blk, 0, stream>>>(A, D, 1);
  off_deform(C, D, 2, F);

  // layer 3: aligned = deform(fea3, conv(fea3))     F -> C
  regroup_k<<<32768, blk, 0, stream>>>(F, D, 0);
  off_deform(F, D, 3, C);

  // recon conv: aligned -> im (8,3,HW)   [VALU fp32, Cout=3]
  conv3x3_k<64, 8, 4, false, false><<<dim3(4, 4, 8), blk, 0, stream>>>(
      C, rcw, rcb, nullptr, im, 3, 1, 0, 0);

  // assemble outputs
  assemble_k<<<42880, blk, 0, stream>>>(x, im, A, F, out);
}

// Round 6
// 2154.982 us; speedup vs baseline: 2.5962x; 1.1581x over previous
//
#include <hip/hip_runtime.h>

#define HH 128
#define WW 128
#define HWX (HH*WW)

using f32x4 = __attribute__((ext_vector_type(4))) float;
using f16x8 = __attribute__((ext_vector_type(8))) _Float16;

__device__ __forceinline__ unsigned short f16bits(_Float16 h) {
  union { _Float16 f; unsigned short u; } v; v.f = h; return v.u;
}

// chunk swizzle: position pos (64B row of 32 f16), chunk q (16B of 8 f16)
__device__ __forceinline__ int swz(int pos, int q) {
  return pos * 32 + (((q + pos + (pos >> 2)) & 3) << 3);
}

// ---------------------------------------------------------------------------
// Weight prep: OIHW fp32 -> [layer][kpos][O][I] split-fp16 (hi + lo arenas)
// ---------------------------------------------------------------------------
__global__ __launch_bounds__(256) void wprep_k(
    const float* __restrict__ src, unsigned short* __restrict__ dhi,
    unsigned short* __restrict__ dlo, int O, int I, int L)
{
  int idx = blockIdx.x * 256 + threadIdx.x;
  int tot = L * O * I * 9;
  if (idx >= tot) return;
  int per = O * I * 9;
  int layer = idx / per;
  int r = idx - layer * per;
  int o = r / (I * 9);
  int r2 = r - o * (I * 9);
  int i = r2 / 9, k = r2 - i * 9;
  float v = src[idx];
  _Float16 h = (_Float16)v;
  _Float16 l = (_Float16)(v - (float)h);
  long di = (long)layer * per + ((long)k * O + o) * I + i;
  dhi[di] = f16bits(h);
  dlo[di] = f16bits(l);
}

// ---------------------------------------------------------------------------
// Deform weight prep: [L][O=64][I=64][9] fp32 -> [L][k2][o][r=I] split-fp16
// ---------------------------------------------------------------------------
__global__ __launch_bounds__(256) void dwprep_k(
    const float* __restrict__ src, unsigned short* __restrict__ dhi,
    unsigned short* __restrict__ dlo)
{
  int idx = blockIdx.x * 256 + threadIdx.x;      // 4*36864 = 147456
  if (idx >= 147456) return;
  int l = idx / 36864;
  int rem = idx - l * 36864;
  int o = rem / 576;
  int rem2 = rem - o * 576;
  int r = rem2 / 9, k2 = rem2 - r * 9;
  float v = src[idx];
  _Float16 h = (_Float16)v;
  _Float16 lo = (_Float16)(v - (float)h);
  long di = (((long)l * 9 + k2) * 64 + o) * 64 + r;
  dhi[di] = f16bits(h);
  dlo[di] = f16bits(lo);
}

// ---------------------------------------------------------------------------
// Split-fp16 MFMA implicit-GEMM 3x3 SAME conv. Block 256 thr = 4 waves.
// ---------------------------------------------------------------------------
template<int CBLK, int NFRAG, bool RELU, bool ADD, bool CRMODE>
__global__ __launch_bounds__(256, 2) void conv_mfma_k(
    const float* __restrict__ in, const unsigned short* __restrict__ whi,
    const unsigned short* __restrict__ wlo,
    const float* __restrict__ bias, const float* __restrict__ res,
    float* __restrict__ out, int Cout, int nslice, int img_in0, int img_out0)
{
  constexpr int CIN = CBLK * 32;
  constexpr int OCB = NFRAG * 16;
  constexpr int WHALF = 9 * OCB * 32;
  __shared__ __align__(16) unsigned short s_in[2 * 10880];   // 10x34 halo, hi|lo
  __shared__ __align__(16) unsigned short s_w[2 * WHALF];    // hi|lo

  const int tid = threadIdx.x;
  const int lane = tid & 63;
  const int wv = tid >> 6;
  const int m16 = lane & 15, q = lane >> 4;
  const int iz = blockIdx.z / nslice, slice = blockIdx.z % nslice;
  const int oc_blk0 = slice * OCB;
  const int x0 = blockIdx.x * 32, y0 = blockIdx.y * 8;

  f32x4 acc[4][NFRAG];
#pragma unroll
  for (int mt = 0; mt < 4; ++mt)
#pragma unroll
    for (int nt = 0; nt < NFRAG; ++nt)
#pragma unroll
      for (int i = 0; i < 4; ++i) acc[mt][nt][i] = 0.f;

  int bb = 0, nn = 0;
  const float* inb = in;
  if (CRMODE) {
    int j = img_in0 + iz;
    bb = j >> 2;
    int ns = j & 3;
    nn = ns < 2 ? ns : ns + 1;
  } else {
    inb = in + (long)(img_in0 + iz) * CIN * HWX;
  }

  for (int cb = 0; cb < CBLK; ++cb) {
    const int c0 = cb * 32;
    __syncthreads();
    for (int t = tid; t < 1360; t += 256) {
      int qq = t / 340, pos = t - qq * 340;
      int iy = pos / 34, ix = pos - iy * 34;
      int gy = y0 + iy - 1, gx = x0 + ix - 1;
      bool inr = (gy >= 0 && gy < HH && gx >= 0 && gx < WW);
      const float* src;
      if (CRMODE) {
        int ch = c0 + qq * 8;
        int simg = (ch < 64) ? (bb * 5 + 2) : (bb * 5 + nn);
        src = in + ((long)simg * 64 + (ch & 63)) * HWX + gy * WW + gx;
      } else {
        src = inb + (long)(c0 + qq * 8) * HWX + gy * WW + gx;
      }
      unsigned hi4[4], lo4[4];
#pragma unroll
      for (int j2 = 0; j2 < 4; ++j2) {
        unsigned short hs[2], ls[2];
#pragma unroll
        for (int j = 0; j < 2; ++j) {
          float v = inr ? src[(long)(j2 * 2 + j) * HWX] : 0.f;
          _Float16 h = (_Float16)v;
          _Float16 l = (_Float16)(v - (float)h);
          hs[j] = f16bits(h); ls[j] = f16bits(l);
        }
        hi4[j2] = (unsigned)hs[0] | ((unsigned)hs[1] << 16);
        lo4[j2] = (unsigned)ls[0] | ((unsigned)ls[1] << 16);
      }
      *(uint4*)(s_in + swz(pos, qq)) = make_uint4(hi4[0], hi4[1], hi4[2], hi4[3]);
      *(uint4*)(s_in + 10880 + swz(pos, qq)) =
          make_uint4(lo4[0], lo4[1], lo4[2], lo4[3]);
    }
    for (int t = tid; t < 9 * OCB * 4; t += 256) {
      int qq = t / (9 * OCB), pw = t - qq * (9 * OCB);
      int kp = pw / OCB, ocl = pw - kp * OCB;
      long so = ((long)kp * Cout + oc_blk0 + ocl) * CIN + c0 + qq * 8;
      *(uint4*)(s_w + swz(pw, qq)) = *(const uint4*)(whi + so);
      *(uint4*)(s_w + WHALF + swz(pw, qq)) = *(const uint4*)(wlo + so);
    }
    __syncthreads();

#pragma unroll
    for (int kp = 0; kp < 9; ++kp) {
      const int dy = kp / 3, dx = kp - dy * 3;
      f16x8 bhi[NFRAG], blo[NFRAG];
#pragma unroll
      for (int nt = 0; nt < NFRAG; ++nt) {
        int pw = kp * OCB + nt * 16 + m16;
        bhi[nt] = *(const f16x8*)(s_w + swz(pw, q));
        blo[nt] = *(const f16x8*)(s_w + WHALF + swz(pw, q));
      }
#pragma unroll
      for (int mt = 0; mt < 4; ++mt) {
        int r = 2 * wv + (mt >> 1), h = mt & 1;
        int pos = (r + dy) * 34 + h * 16 + m16 + dx;
        f16x8 ahi = *(const f16x8*)(s_in + swz(pos, q));
        f16x8 alo = *(const f16x8*)(s_in + 10880 + swz(pos, q));
#pragma unroll
        for (int nt = 0; nt < NFRAG; ++nt) {
          acc[mt][nt] = __builtin_amdgcn_mfma_f32_16x16x32_f16(
              ahi, blo[nt], acc[mt][nt], 0, 0, 0);
          acc[mt][nt] = __builtin_amdgcn_mfma_f32_16x16x32_f16(
              alo, bhi[nt], acc[mt][nt], 0, 0, 0);
          acc[mt][nt] = __builtin_amdgcn_mfma_f32_16x16x32_f16(
              ahi, bhi[nt], acc[mt][nt], 0, 0, 0);
        }
      }
    }
  }

  const int img_o = img_out0 + iz;
#pragma unroll
  for (int mt = 0; mt < 4; ++mt) {
    int r = 2 * wv + (mt >> 1), h = mt & 1;
    int y = y0 + r;
    int xb = x0 + h * 16 + q * 4;
#pragma unroll
    for (int nt = 0; nt < NFRAG; ++nt) {
      int oc = oc_blk0 + nt * 16 + m16;
      if (oc < Cout) {
        float bsv = bias[oc];
        long base = ((long)img_o * Cout + oc) * HWX + (long)y * WW + xb;
#pragma unroll
        for (int i = 0; i < 4; ++i) {
          float v = acc[mt][nt][i] + bsv;
          if (RELU) v = fmaxf(v, 0.f);
          if (ADD) v += res[base + i];
          out[base + i] = v;
        }
      }
    }
  }
}

// ---------------------------------------------------------------------------
// Fallback VALU conv (conv_first CIN=3 and recon Cout=3).
// ---------------------------------------------------------------------------
template<int CIN, int CK, int OCB, bool RELU, bool ADD>
__global__ __launch_bounds__(256) void conv3x3_k(
    const float* __restrict__ in, const float* __restrict__ wgt,
    const float* __restrict__ bias, const float* __restrict__ res,
    float* __restrict__ out, int Cout, int nslice, int img_in0, int img_out0)
{
  __shared__ __align__(16) float s_in[CK][34][34];
  __shared__ __align__(16) float s_w[CK * 9 * OCB];

  const int tid = threadIdx.x;
  const int tx = tid & 31;
  const int ty = tid >> 5;
  const int iz = blockIdx.z / nslice;
  const int slice = blockIdx.z % nslice;
  const int oc0 = slice * OCB;
  const int x0 = blockIdx.x * 32;
  const int y0 = blockIdx.y * 32;

  float acc[4][OCB];
#pragma unroll
  for (int r = 0; r < 4; ++r)
#pragma unroll
    for (int o = 0; o < OCB; ++o) acc[r][o] = 0.f;

  const float* inb = in + (long)(img_in0 + iz) * CIN * HWX;

  for (int c0 = 0; c0 < CIN; c0 += CK) {
    __syncthreads();
    for (int idx = tid; idx < CK * 34 * 34; idx += 256) {
      int c = idx / 1156;
      int rem = idx % 1156;
      int iy = rem / 34, ix = rem % 34;
      int gy = y0 + iy - 1, gx = x0 + ix - 1;
      float v = 0.f;
      if (gy >= 0 && gy < HH && gx >= 0 && gx < WW)
        v = inb[(long)(c0 + c) * HWX + gy * WW + gx];
      s_in[c][iy][ix] = v;
    }
    for (int idx = tid; idx < CK * 9 * OCB; idx += 256) {
      int oc = idx % OCB;
      int ck = idx / OCB;
      int c = ck / 9, k = ck % 9;
      int ocg = oc0 + oc;
      float v = 0.f;
      if (ocg < Cout) v = wgt[((long)ocg * CIN + c0 + c) * 9 + k];
      s_w[idx] = v;
    }
    __syncthreads();

    for (int c = 0; c < CK; ++c) {
#pragma unroll
      for (int k = 0; k < 9; ++k) {
        const int ky = k / 3, kx = k % 3;
        float v0 = s_in[c][ty + ky][tx + kx];
        float v1 = s_in[c][ty + 8 + ky][tx + kx];
        float v2 = s_in[c][ty + 16 + ky][tx + kx];
        float v3 = s_in[c][ty + 24 + ky][tx + kx];
        const float4* wp = (const float4*)&s_w[(c * 9 + k) * OCB];
#pragma unroll
        for (int o4 = 0; o4 < OCB / 4; ++o4) {
          float4 w4 = wp[o4];
          acc[0][o4 * 4 + 0] += v0 * w4.x; acc[0][o4 * 4 + 1] += v0 * w4.y;
          acc[0][o4 * 4 + 2] += v0 * w4.z; acc[0][o4 * 4 + 3] += v0 * w4.w;
          acc[1][o4 * 4 + 0] += v1 * w4.x; acc[1][o4 * 4 + 1] += v1 * w4.y;
          acc[1][o4 * 4 + 2] += v1 * w4.z; acc[1][o4 * 4 + 3] += v1 * w4.w;
          acc[2][o4 * 4 + 0] += v2 * w4.x; acc[2][o4 * 4 + 1] += v2 * w4.y;
          acc[2][o4 * 4 + 2] += v2 * w4.z; acc[2][o4 * 4 + 3] += v2 * w4.w;
          acc[3][o4 * 4 + 0] += v3 * w4.x; acc[3][o4 * 4 + 1] += v3 * w4.y;
          acc[3][o4 * 4 + 2] += v3 * w4.z; acc[3][o4 * 4 + 3] += v3 * w4.w;
        }
      }
    }
  }

#pragma unroll
  for (int o = 0; o < OCB; ++o) {
    int ocg = oc0 + o;
    if (ocg < Cout) {
      float b = bias ? bias[ocg] : 0.f;
      long base = ((long)(img_out0 + iz) * Cout + ocg) * HWX;
#pragma unroll
      for (int r = 0; r < 4; ++r) {
        int y = y0 + ty + 8 * r;
        float v = acc[r][o] + b;
        if (RELU) v = fmaxf(v, 0.f);
        long ia = base + (long)y * WW + x0 + tx;
        if (ADD) v += res[ia];
        out[ia] = v;
      }
    }
  }
}

// ---------------------------------------------------------------------------
__global__ __launch_bounds__(256) void regroup_k(
    const float* __restrict__ src, float* __restrict__ dst, int supp_mode)
{
  int idx = blockIdx.x * 256 + threadIdx.x;
  int c = idx & 7;
  int p = (idx >> 3) & 16383;
  int g = (idx >> 17) & 7;
  int img = idx >> 20;
  int simg = img;
  if (supp_mode) {
    int b = img >> 2, ns = img & 3;
    simg = b * 5 + (ns < 2 ? ns : ns + 1);
  }
  dst[idx] = src[((simg * 64 + g * 8 + c) * HWX) + p];
}

__device__ __forceinline__ void bilin8(const float* __restrict__ sg,
                                       float py, float px, float* sv)
{
  float y0f = floorf(py), x0f = floorf(px);
  float wy = py - y0f, wx = px - x0f;
  float y1f = y0f + 1.f, x1f = x0f + 1.f;
  float my0 = (y0f >= 0.f && y0f <= 127.f) ? 1.f : 0.f;
  float my1 = (y1f >= 0.f && y1f <= 127.f) ? 1.f : 0.f;
  float mx0 = (x0f >= 0.f && x0f <= 127.f) ? 1.f : 0.f;
  float mx1 = (x1f >= 0.f && x1f <= 127.f) ? 1.f : 0.f;
  int yi0 = (int)fminf(fmaxf(y0f, 0.f), 127.f);
  int yi1 = (int)fminf(fmaxf(y1f, 0.f), 127.f);
  int xi0 = (int)fminf(fmaxf(x0f, 0.f), 127.f);
  int xi1 = (int)fminf(fmaxf(x1f, 0.f), 127.f);
  float w00 = (1.f - wy) * (1.f - wx) * my0 * mx0;
  float w01 = (1.f - wy) * wx * my0 * mx1;
  float w10 = wy * (1.f - wx) * my1 * mx0;
  float w11 = wy * wx * my1 * mx1;
  const float4* p00 = (const float4*)(sg + ((long)yi0 * WW + xi0) * 8);
  const float4* p01 = (const float4*)(sg + ((long)yi0 * WW + xi1) * 8);
  const float4* p10 = (const float4*)(sg + ((long)yi1 * WW + xi0) * 8);
  const float4* p11 = (const float4*)(sg + ((long)yi1 * WW + xi1) * 8);
  float4 a00 = p00[0], b00 = p00[1];
  float4 a01 = p01[0], b01 = p01[1];
  float4 a10 = p10[0], b10 = p10[1];
  float4 a11 = p11[0], b11 = p11[1];
  sv[0] = w00 * a00.x + w01 * a01.x + w10 * a10.x + w11 * a11.x;
  sv[1] = w00 * a00.y + w01 * a01.y + w10 * a10.y + w11 * a11.y;
  sv[2] = w00 * a00.z + w01 * a01.z + w10 * a10.z + w11 * a11.z;
  sv[3] = w00 * a00.w + w01 * a01.w + w10 * a10.w + w11 * a11.w;
  sv[4] = w00 * b00.x + w01 * b01.x + w10 * b10.x + w11 * b11.x;
  sv[5] = w00 * b00.y + w01 * b01.y + w10 * b10.y + w11 * b11.y;
  sv[6] = w00 * b00.z + w01 * b01.z + w10 * b10.z + w11 * b11.z;
  sv[7] = w00 * b00.w + w01 * b01.w + w10 * b10.w + w11 * b11.w;
}

// ---------------------------------------------------------------------------
// Deform as split-fp16 MFMA implicit GEMM with fused bilinear sampling.
// v2: (a) all 144 offset channels for the block's 64 px staged in LDS up
// front (OFF read exactly once, no L2 streaming during gather loop);
// (b) 1D grid with img = bid & cmask so blocks of one image land on one XCD
// (round-robin heuristic) -> the image's 4 MB grouped buffer fits that L2.
// ---------------------------------------------------------------------------
__global__ __launch_bounds__(256) void deform_mfma_k(
    const float* __restrict__ srcg, const float* __restrict__ off,
    const unsigned short* __restrict__ wh, const unsigned short* __restrict__ wl,
    float* __restrict__ out, int img0, int cmask, int cshift)
{
  __shared__ __align__(16) float s_off[9216];           // [144][64 px]
  __shared__ __align__(16) unsigned short s_bh[4096];
  __shared__ __align__(16) unsigned short s_bl[4096];
  const int tid = threadIdx.x;
  const int lane = tid & 63;
  const int wv = tid >> 6;
  const int m16 = lane & 15, q = lane >> 4;
  const int bid = blockIdx.x;
  const int iz = bid & cmask;
  const int tile = bid >> cshift;
  const int img = img0 + iz;
  const int tp0 = tile * 64;
  const int pl = wv * 16 + m16;          // local px 0..63
  const int p = tp0 + pl;
  const float fy = (float)(p >> 7), fx = (float)(p & 127);
  const int rot = 8 * (m16 & 7);

  // stage this tile's offsets: s_off[c][j] = OFF[iz][c][tp0+j]
  {
    const float* ob = off + (long)iz * 144 * HWX + tp0;
    for (int t = tid; t < 2304; t += 256) {            // 144 ch x 16 float4
      int c = t >> 4, j = t & 15;
      *(float4*)(s_off + c * 64 + 4 * j) =
          *(const float4*)(ob + (long)c * HWX + 4 * j);
    }
  }

  f32x4 acc[4];
#pragma unroll
  for (int nt = 0; nt < 4; ++nt)
#pragma unroll
    for (int i = 0; i < 4; ++i) acc[nt][i] = 0.f;

  for (int k2 = 0; k2 < 9; ++k2) {
    __syncthreads();
    // stage weight slab [o=64][r=64] hi+lo, rotated by o within 64-f16 rows
    for (int t = tid; t < 512; t += 256) {
      int o = t >> 3, j = t & 7;
      int d = o * 64 + ((8 * j + 8 * (o & 7)) & 63);
      long so = ((long)k2 * 64 + o) * 64 + 8 * j;
      *(uint4*)(s_bh + d) = *(const uint4*)(wh + so);
      *(uint4*)(s_bl + d) = *(const uint4*)(wl + so);
    }
    __syncthreads();
    const float kyf = (float)(k2 / 3 - 1), kxf = (float)(k2 % 3 - 1);
#pragma unroll
    for (int s = 0; s < 2; ++s) {
      const int g = 4 * s + q;
      float dyv = s_off[(g * 18 + 2 * k2) * 64 + pl];
      float dxv = s_off[(g * 18 + 2 * k2 + 1) * 64 + pl];
      float sv[8];
      bilin8(srcg + (long)(img * 8 + g) * HWX * 8,
             dyv + fy + kyf, dxv + fx + kxf, sv);
      f16x8 ah, al;
#pragma unroll
      for (int j = 0; j < 8; ++j) {
        _Float16 h = (_Float16)sv[j];
        _Float16 l = (_Float16)(sv[j] - (float)h);
        ah[j] = h; al[j] = l;
      }
      const int roff = (32 * s + 8 * q + rot) & 63;
#pragma unroll
      for (int nt = 0; nt < 4; ++nt) {
        int o = nt * 16 + m16;
        f16x8 bh = *(const f16x8*)(s_bh + o * 64 + roff);
        f16x8 bl = *(const f16x8*)(s_bl + o * 64 + roff);
        acc[nt] = __builtin_amdgcn_mfma_f32_16x16x32_f16(ah, bl, acc[nt], 0, 0, 0);
        acc[nt] = __builtin_amdgcn_mfma_f32_16x16x32_f16(al, bh, acc[nt], 0, 0, 0);
        acc[nt] = __builtin_amdgcn_mfma_f32_16x16x32_f16(ah, bh, acc[nt], 0, 0, 0);
      }
    }
  }

  const long pb = tp0 + wv * 16 + q * 4;
#pragma unroll
  for (int nt = 0; nt < 4; ++nt) {
    int oc = nt * 16 + m16;
    float4 v;
    v.x = acc[nt][0]; v.y = acc[nt][1]; v.z = acc[nt][2]; v.w = acc[nt][3];
    *(float4*)(out + ((long)img * 64 + oc) * HWX + pb) = v;
  }
}

__global__ __launch_bounds__(256) void assemble_k(
    const float* __restrict__ x, const float* __restrict__ im,
    const float* __restrict__ out0, const float* __restrict__ fea,
    float* __restrict__ out)
{
  int idx = blockIdx.x * 256 + threadIdx.x;
  if (idx < 491520) {
    int within = idx % 49152;
    int n = (idx / 49152) % 5;
    int b = idx / (49152 * 5);
    float v;
    if (n == 2) v = x[(b * 5 + 2) * 49152 + within];
    else {
      int j = b * 4 + (n < 2 ? n : n - 1);
      v = im[j * 49152 + within];
    }
    out[idx] = v;
  } else if (idx < 10977280) {
    int idx2 = idx - 491520;
    int within = idx2 % 1048576;
    int n = (idx2 / 1048576) % 5;
    int b = idx2 / (1048576 * 5);
    float v;
    if (n == 2) v = out0[(b * 5 + 2) * 1048576 + within];
    else {
      int j = b * 4 + (n < 2 ? n : n - 1);
      v = fea[j * 1048576 + within];
    }
    out[idx] = v;
  }
}

// ---------------------------------------------------------------------------
extern "C" void kernel_launch(void* const* d_in, const int* in_sizes, int n_in,
                              void* d_out, int out_size, void* d_ws, size_t ws_size,
                              hipStream_t stream) {
  const float* x   = (const float*)d_in[0];
  const float* cfw = (const float*)d_in[1];
  const float* cfb = (const float*)d_in[2];
  const float* rw1 = (const float*)d_in[3];
  const float* rb1 = (const float*)d_in[4];
  const float* rw2 = (const float*)d_in[5];
  const float* rb2 = (const float*)d_in[6];
  const float* crw = (const float*)d_in[7];
  const float* crb = (const float*)d_in[8];
  const float* ofw = (const float*)d_in[9];
  const float* ofb = (const float*)d_in[10];
  const float* dcw = (const float*)d_in[11];
  const float* rcw = (const float*)d_in[12];
  const float* rcb = (const float*)d_in[13];
  float* out = (float*)d_out;

  // conv weight arenas (hi|lo), then deform weight arenas (hi|lo)
  unsigned short* WH = (unsigned short*)d_ws;
  unsigned short* WL = WH + 774144;
  unsigned short* DH = WH + 1548288;
  unsigned short* DL = DH + 147456;
  const long W_res1 = 0, W_res2 = 184320, W_cr = 368640, W_off = 442368;

  float* A = (float*)d_ws + 921600;                  // (10,64,HW)
  float* C = A + 10485760;                           // fea ping (8,64,HW)
  float* D = C + 8388608;                            // grouped / im
  float* F = D + 8388608;                            // fea3
  float* OFF = F + 8388608;                          // offsets (chunk,144,HW)
  float* r = C;
  float* im = D;

  const size_t fixedF = 921600UL + 10485760UL + 3UL * 8388608UL;
  int chunk = 8;
  while (chunk > 1 && (fixedF + (size_t)chunk * 2359296UL) * sizeof(float) > ws_size)
    chunk >>= 1;
  int cshift = (chunk == 8) ? 3 : (chunk == 4) ? 2 : (chunk == 2) ? 1 : 0;

  dim3 blk(256);

  // weight prep
  wprep_k<<<720, blk, 0, stream>>>(rw1, WH + W_res1, WL + W_res1, 64, 64, 5);
  wprep_k<<<720, blk, 0, stream>>>(rw2, WH + W_res2, WL + W_res2, 64, 64, 5);
  wprep_k<<<288, blk, 0, stream>>>(crw, WH + W_cr, WL + W_cr, 64, 128, 1);
  wprep_k<<<1296, blk, 0, stream>>>(ofw, WH + W_off, WL + W_off, 144, 64, 4);
  dwprep_k<<<576, blk, 0, stream>>>(dcw, DH, DL);

  // conv_first + ReLU : x (10,3,HW) -> A (10,64,HW)   [VALU fp32, CIN=3]
  conv3x3_k<3, 3, 16, true, false><<<dim3(4, 4, 40), blk, 0, stream>>>(
      x, cfw, cfb, nullptr, A, 64, 4, 0, 0);

  // 5 residual blocks (split-fp16 MFMA)
  for (int i = 0; i < 5; ++i) {
    conv_mfma_k<2, 2, true, false, false><<<dim3(4, 16, 20), blk, 0, stream>>>(
        A, WH + W_res1 + (long)i * 36864, WL + W_res1 + (long)i * 36864,
        rb1 + i * 64, nullptr, r, 64, 2, 0, 0);
    conv_mfma_k<2, 2, false, true, false><<<dim3(4, 16, 20), blk, 0, stream>>>(
        r, WH + W_res2 + (long)i * 36864, WL + W_res2 + (long)i * 36864,
        rb2 + i * 64, A, A, 64, 2, 0, 0);
  }

  // cr conv, fused concat(ref,supp): A -> C (fea0)
  conv_mfma_k<4, 2, false, false, true><<<dim3(4, 16, 16), blk, 0, stream>>>(
      A, WH + W_cr, WL + W_cr, crb, nullptr, C, 64, 2, 0, 0);

  // offset conv (split-fp16 MFMA, 144ch = 3x48) + deform (MFMA), chunked
  auto off_deform = [&](const float* fea_in, const float* grouped,
                        int layer, float* outp) {
    for (int i0 = 0; i0 < 8; i0 += chunk) {
      conv_mfma_k<2, 3, false, false, false>
          <<<dim3(4, 16, chunk * 3), blk, 0, stream>>>(
              fea_in, WH + W_off + (long)layer * 82944,
              WL + W_off + (long)layer * 82944, ofb + layer * 144,
              nullptr, OFF, 144, 3, i0, 0);
      deform_mfma_k<<<dim3(256 * chunk), blk, 0, stream>>>(
          grouped, OFF, DH + (long)layer * 36864, DL + (long)layer * 36864,
          outp, i0, chunk - 1, cshift);
    }
  };

  // layer 0: fea1 = deform(fea0, conv(fea0))        C -> C
  regroup_k<<<32768, blk, 0, stream>>>(C, D, 0);
  off_deform(C, D, 0, C);

  // layer 1: fea2 = deform(fea1, conv(fea1))        C -> C
  regroup_k<<<32768, blk, 0, stream>>>(C, D, 0);
  off_deform(C, D, 1, C);

  // layer 2: fea3 = deform(supp, conv(fea2))        (A supp, C) -> F
  regroup_k<<<32768, blk, 0, stream>>>(A, D, 1);
  off_deform(C, D, 2, F);

  // layer 3: aligned = deform(fea3, conv(fea3))     F -> C
  regroup_k<<<32768, blk, 0, stream>>>(F, D, 0);
  off_deform(F, D, 3, C);

  // recon conv: aligned -> im (8,3,HW)   [VALU fp32, Cout=3]
  conv3x3_k<64, 8, 4, false, false><<<dim3(4, 4, 8), blk, 0, stream>>>(
      C, rcw, rcb, nullptr, im, 3, 1, 0, 0);

  // assemble outputs
  assemble_k<<<42880, blk, 0, stream>>>(x, im, A, F, out);
}

// Round 7
// 2004.988 us; speedup vs baseline: 2.7904x; 1.0748x over previous
//
#include <hip/hip_runtime.h>

#define HH 128
#define WW 128
#define HWX (HH*WW)

using f32x4 = __attribute__((ext_vector_type(4))) float;
using f16x8 = __attribute__((ext_vector_type(8))) _Float16;

__device__ __forceinline__ unsigned short f16bits(_Float16 h) {
  union { _Float16 f; unsigned short u; } v; v.f = h; return v.u;
}

// chunk swizzle: position pos (64B row of 32 f16), chunk q (16B of 8 f16)
__device__ __forceinline__ int swz(int pos, int q) {
  return pos * 32 + (((q + pos + (pos >> 2)) & 3) << 3);
}

// ---------------------------------------------------------------------------
// Weight prep: OIHW fp32 -> [layer][kpos][O][I] split-fp16 (hi + lo arenas)
// ---------------------------------------------------------------------------
__global__ __launch_bounds__(256) void wprep_k(
    const float* __restrict__ src, unsigned short* __restrict__ dhi,
    unsigned short* __restrict__ dlo, int O, int I, int L)
{
  int idx = blockIdx.x * 256 + threadIdx.x;
  int tot = L * O * I * 9;
  if (idx >= tot) return;
  int per = O * I * 9;
  int layer = idx / per;
  int r = idx - layer * per;
  int o = r / (I * 9);
  int r2 = r - o * (I * 9);
  int i = r2 / 9, k = r2 - i * 9;
  float v = src[idx];
  _Float16 h = (_Float16)v;
  _Float16 l = (_Float16)(v - (float)h);
  long di = (long)layer * per + ((long)k * O + o) * I + i;
  dhi[di] = f16bits(h);
  dlo[di] = f16bits(l);
}

// ---------------------------------------------------------------------------
// Deform weight prep: [L][O=64][I=64][9] fp32 -> [L][k2][o][r=I] split-fp16
// ---------------------------------------------------------------------------
__global__ __launch_bounds__(256) void dwprep_k(
    const float* __restrict__ src, unsigned short* __restrict__ dhi,
    unsigned short* __restrict__ dlo)
{
  int idx = blockIdx.x * 256 + threadIdx.x;      // 4*36864 = 147456
  if (idx >= 147456) return;
  int l = idx / 36864;
  int rem = idx - l * 36864;
  int o = rem / 576;
  int rem2 = rem - o * 576;
  int r = rem2 / 9, k2 = rem2 - r * 9;
  float v = src[idx];
  _Float16 h = (_Float16)v;
  _Float16 lo = (_Float16)(v - (float)h);
  long di = (((long)l * 9 + k2) * 64 + o) * 64 + r;
  dhi[di] = f16bits(h);
  dlo[di] = f16bits(lo);
}

// ---------------------------------------------------------------------------
// Split-fp16 MFMA implicit-GEMM 3x3 SAME conv. Block 256 thr = 4 waves.
// px tile 32x8; wave: 64 px x OCB oc. Weights staged per-kp, double-buffered
// (LDS: s_in 43.5 KB + s_w 2x2xSLAB -> <=60 KB total => 2 blocks/CU).
// Each logical product = 3 MFMAs: Ahi*Blo + Alo*Bhi + Ahi*Bhi (fp32 acc).
// ---------------------------------------------------------------------------
template<int CBLK, int NFRAG, bool RELU, bool ADD, bool CRMODE>
__global__ __launch_bounds__(256, 2) void conv_mfma_k(
    const float* __restrict__ in, const unsigned short* __restrict__ whi,
    const unsigned short* __restrict__ wlo,
    const float* __restrict__ bias, const float* __restrict__ res,
    float* __restrict__ out, int Cout, int nslice, int img_in0, int img_out0)
{
  constexpr int CIN = CBLK * 32;
  constexpr int OCB = NFRAG * 16;
  constexpr int SLAB = OCB * 32;               // ushorts per (buf,half)
  __shared__ __align__(16) unsigned short s_in[2 * 10880];   // 10x34 halo hi|lo
  __shared__ __align__(16) unsigned short s_w[2][2 * SLAB];  // [buf][hi|lo]

  const int tid = threadIdx.x;
  const int lane = tid & 63;
  const int wv = tid >> 6;
  const int m16 = lane & 15, q = lane >> 4;
  const int iz = blockIdx.z / nslice, slice = blockIdx.z % nslice;
  const int oc_blk0 = slice * OCB;
  const int x0 = blockIdx.x * 32, y0 = blockIdx.y * 8;

  f32x4 acc[4][NFRAG];
#pragma unroll
  for (int mt = 0; mt < 4; ++mt)
#pragma unroll
    for (int nt = 0; nt < NFRAG; ++nt)
#pragma unroll
      for (int i = 0; i < 4; ++i) acc[mt][nt][i] = 0.f;

  int bb = 0, nn = 0;
  const float* inb = in;
  if (CRMODE) {
    int j = img_in0 + iz;
    bb = j >> 2;
    int ns = j & 3;
    nn = ns < 2 ? ns : ns + 1;
  } else {
    inb = in + (long)(img_in0 + iz) * CIN * HWX;
  }

  for (int cb = 0; cb < CBLK; ++cb) {
    const int c0 = cb * 32;
    // ---- stage input tile: fp32 -> (hi,lo) fp16, channels-last, swizzled ----
    for (int t = tid; t < 1360; t += 256) {
      int qq = t / 340, pos = t - qq * 340;
      int iy = pos / 34, ix = pos - iy * 34;
      int gy = y0 + iy - 1, gx = x0 + ix - 1;
      bool inr = (gy >= 0 && gy < HH && gx >= 0 && gx < WW);
      const float* src;
      if (CRMODE) {
        int ch = c0 + qq * 8;
        int simg = (ch < 64) ? (bb * 5 + 2) : (bb * 5 + nn);
        src = in + ((long)simg * 64 + (ch & 63)) * HWX + gy * WW + gx;
      } else {
        src = inb + (long)(c0 + qq * 8) * HWX + gy * WW + gx;
      }
      unsigned hi4[4], lo4[4];
#pragma unroll
      for (int j2 = 0; j2 < 4; ++j2) {
        unsigned short hs[2], ls[2];
#pragma unroll
        for (int j = 0; j < 2; ++j) {
          float v = inr ? src[(long)(j2 * 2 + j) * HWX] : 0.f;
          _Float16 h = (_Float16)v;
          _Float16 l = (_Float16)(v - (float)h);
          hs[j] = f16bits(h); ls[j] = f16bits(l);
        }
        hi4[j2] = (unsigned)hs[0] | ((unsigned)hs[1] << 16);
        lo4[j2] = (unsigned)ls[0] | ((unsigned)ls[1] << 16);
      }
      *(uint4*)(s_in + swz(pos, qq)) = make_uint4(hi4[0], hi4[1], hi4[2], hi4[3]);
      *(uint4*)(s_in + 10880 + swz(pos, qq)) =
          make_uint4(lo4[0], lo4[1], lo4[2], lo4[3]);
    }
    // ---- stage kp=0 weight slab into buf 0 ----
    for (int t = tid; t < OCB * 4; t += 256) {
      int qq = t & 3, ocl = t >> 2;
      long so = ((long)0 * Cout + oc_blk0 + ocl) * CIN + c0 + qq * 8;
      *(uint4*)(s_w[0] + swz(ocl, qq)) = *(const uint4*)(whi + so);
      *(uint4*)(s_w[0] + SLAB + swz(ocl, qq)) = *(const uint4*)(wlo + so);
    }
    __syncthreads();

#pragma unroll
    for (int kp = 0; kp < 9; ++kp) {
      // prefetch next slab into the other buffer (no barrier needed here:
      // writes go to buf^1 which no one reads until after the end barrier)
      if (kp < 8) {
        const int buf = (kp + 1) & 1;
        for (int t = tid; t < OCB * 4; t += 256) {
          int qq = t & 3, ocl = t >> 2;
          long so = ((long)(kp + 1) * Cout + oc_blk0 + ocl) * CIN + c0 + qq * 8;
          *(uint4*)(s_w[buf] + swz(ocl, qq)) = *(const uint4*)(whi + so);
          *(uint4*)(s_w[buf] + SLAB + swz(ocl, qq)) = *(const uint4*)(wlo + so);
        }
      }
      const unsigned short* wb = s_w[kp & 1];
      const int dy = kp / 3, dx = kp - dy * 3;
      f16x8 bhi[NFRAG], blo[NFRAG];
#pragma unroll
      for (int nt = 0; nt < NFRAG; ++nt) {
        int pw = nt * 16 + m16;
        bhi[nt] = *(const f16x8*)(wb + swz(pw, q));
        blo[nt] = *(const f16x8*)(wb + SLAB + swz(pw, q));
      }
#pragma unroll
      for (int mt = 0; mt < 4; ++mt) {
        int r = 2 * wv + (mt >> 1), h = mt & 1;
        int pos = (r + dy) * 34 + h * 16 + m16 + dx;
        f16x8 ahi = *(const f16x8*)(s_in + swz(pos, q));
        f16x8 alo = *(const f16x8*)(s_in + 10880 + swz(pos, q));
#pragma unroll
        for (int nt = 0; nt < NFRAG; ++nt) {
          acc[mt][nt] = __builtin_amdgcn_mfma_f32_16x16x32_f16(
              ahi, blo[nt], acc[mt][nt], 0, 0, 0);
          acc[mt][nt] = __builtin_amdgcn_mfma_f32_16x16x32_f16(
              alo, bhi[nt], acc[mt][nt], 0, 0, 0);
          acc[mt][nt] = __builtin_amdgcn_mfma_f32_16x16x32_f16(
              ahi, bhi[nt], acc[mt][nt], 0, 0, 0);
        }
      }
      __syncthreads();
    }
  }

  const int img_o = img_out0 + iz;
#pragma unroll
  for (int mt = 0; mt < 4; ++mt) {
    int r = 2 * wv + (mt >> 1), h = mt & 1;
    int y = y0 + r;
    int xb = x0 + h * 16 + q * 4;
#pragma unroll
    for (int nt = 0; nt < NFRAG; ++nt) {
      int oc = oc_blk0 + nt * 16 + m16;
      if (oc < Cout) {
        float bsv = bias[oc];
        long base = ((long)img_o * Cout + oc) * HWX + (long)y * WW + xb;
#pragma unroll
        for (int i = 0; i < 4; ++i) {
          float v = acc[mt][nt][i] + bsv;
          if (RELU) v = fmaxf(v, 0.f);
          if (ADD) v += res[base + i];
          out[base + i] = v;
        }
      }
    }
  }
}

// ---------------------------------------------------------------------------
// Fallback VALU conv (conv_first CIN=3 and recon Cout=3).
// ---------------------------------------------------------------------------
template<int CIN, int CK, int OCB, bool RELU, bool ADD>
__global__ __launch_bounds__(256) void conv3x3_k(
    const float* __restrict__ in, const float* __restrict__ wgt,
    const float* __restrict__ bias, const float* __restrict__ res,
    float* __restrict__ out, int Cout, int nslice, int img_in0, int img_out0)
{
  __shared__ __align__(16) float s_in[CK][34][34];
  __shared__ __align__(16) float s_w[CK * 9 * OCB];

  const int tid = threadIdx.x;
  const int tx = tid & 31;
  const int ty = tid >> 5;
  const int iz = blockIdx.z / nslice;
  const int slice = blockIdx.z % nslice;
  const int oc0 = slice * OCB;
  const int x0 = blockIdx.x * 32;
  const int y0 = blockIdx.y * 32;

  float acc[4][OCB];
#pragma unroll
  for (int r = 0; r < 4; ++r)
#pragma unroll
    for (int o = 0; o < OCB; ++o) acc[r][o] = 0.f;

  const float* inb = in + (long)(img_in0 + iz) * CIN * HWX;

  for (int c0 = 0; c0 < CIN; c0 += CK) {
    __syncthreads();
    for (int idx = tid; idx < CK * 34 * 34; idx += 256) {
      int c = idx / 1156;
      int rem = idx % 1156;
      int iy = rem / 34, ix = rem % 34;
      int gy = y0 + iy - 1, gx = x0 + ix - 1;
      float v = 0.f;
      if (gy >= 0 && gy < HH && gx >= 0 && gx < WW)
        v = inb[(long)(c0 + c) * HWX + gy * WW + gx];
      s_in[c][iy][ix] = v;
    }
    for (int idx = tid; idx < CK * 9 * OCB; idx += 256) {
      int oc = idx % OCB;
      int ck = idx / OCB;
      int c = ck / 9, k = ck % 9;
      int ocg = oc0 + oc;
      float v = 0.f;
      if (ocg < Cout) v = wgt[((long)ocg * CIN + c0 + c) * 9 + k];
      s_w[idx] = v;
    }
    __syncthreads();

    for (int c = 0; c < CK; ++c) {
#pragma unroll
      for (int k = 0; k < 9; ++k) {
        const int ky = k / 3, kx = k % 3;
        float v0 = s_in[c][ty + ky][tx + kx];
        float v1 = s_in[c][ty + 8 + ky][tx + kx];
        float v2 = s_in[c][ty + 16 + ky][tx + kx];
        float v3 = s_in[c][ty + 24 + ky][tx + kx];
        const float4* wp = (const float4*)&s_w[(c * 9 + k) * OCB];
#pragma unroll
        for (int o4 = 0; o4 < OCB / 4; ++o4) {
          float4 w4 = wp[o4];
          acc[0][o4 * 4 + 0] += v0 * w4.x; acc[0][o4 * 4 + 1] += v0 * w4.y;
          acc[0][o4 * 4 + 2] += v0 * w4.z; acc[0][o4 * 4 + 3] += v0 * w4.w;
          acc[1][o4 * 4 + 0] += v1 * w4.x; acc[1][o4 * 4 + 1] += v1 * w4.y;
          acc[1][o4 * 4 + 2] += v1 * w4.z; acc[1][o4 * 4 + 3] += v1 * w4.w;
          acc[2][o4 * 4 + 0] += v2 * w4.x; acc[2][o4 * 4 + 1] += v2 * w4.y;
          acc[2][o4 * 4 + 2] += v2 * w4.z; acc[2][o4 * 4 + 3] += v2 * w4.w;
          acc[3][o4 * 4 + 0] += v3 * w4.x; acc[3][o4 * 4 + 1] += v3 * w4.y;
          acc[3][o4 * 4 + 2] += v3 * w4.z; acc[3][o4 * 4 + 3] += v3 * w4.w;
        }
      }
    }
  }

#pragma unroll
  for (int o = 0; o < OCB; ++o) {
    int ocg = oc0 + o;
    if (ocg < Cout) {
      float b = bias ? bias[ocg] : 0.f;
      long base = ((long)(img_out0 + iz) * Cout + ocg) * HWX;
#pragma unroll
      for (int r = 0; r < 4; ++r) {
        int y = y0 + ty + 8 * r;
        float v = acc[r][o] + b;
        if (RELU) v = fmaxf(v, 0.f);
        long ia = base + (long)y * WW + x0 + tx;
        if (ADD) v += res[ia];
        out[ia] = v;
      }
    }
  }
}

// ---------------------------------------------------------------------------
__global__ __launch_bounds__(256) void regroup_k(
    const float* __restrict__ src, float* __restrict__ dst, int supp_mode)
{
  int idx = blockIdx.x * 256 + threadIdx.x;
  int c = idx & 7;
  int p = (idx >> 3) & 16383;
  int g = (idx >> 17) & 7;
  int img = idx >> 20;
  int simg = img;
  if (supp_mode) {
    int b = img >> 2, ns = img & 3;
    simg = b * 5 + (ns < 2 ? ns : ns + 1);
  }
  dst[idx] = src[((simg * 64 + g * 8 + c) * HWX) + p];
}

__device__ __forceinline__ void bilin8(const float* __restrict__ sg,
                                       float py, float px, float* sv)
{
  float y0f = floorf(py), x0f = floorf(px);
  float wy = py - y0f, wx = px - x0f;
  float y1f = y0f + 1.f, x1f = x0f + 1.f;
  float my0 = (y0f >= 0.f && y0f <= 127.f) ? 1.f : 0.f;
  float my1 = (y1f >= 0.f && y1f <= 127.f) ? 1.f : 0.f;
  float mx0 = (x0f >= 0.f && x0f <= 127.f) ? 1.f : 0.f;
  float mx1 = (x1f >= 0.f && x1f <= 127.f) ? 1.f : 0.f;
  int yi0 = (int)fminf(fmaxf(y0f, 0.f), 127.f);
  int yi1 = (int)fminf(fmaxf(y1f, 0.f), 127.f);
  int xi0 = (int)fminf(fmaxf(x0f, 0.f), 127.f);
  int xi1 = (int)fminf(fmaxf(x1f, 0.f), 127.f);
  float w00 = (1.f - wy) * (1.f - wx) * my0 * mx0;
  float w01 = (1.f - wy) * wx * my0 * mx1;
  float w10 = wy * (1.f - wx) * my1 * mx0;
  float w11 = wy * wx * my1 * mx1;
  const float4* p00 = (const float4*)(sg + ((long)yi0 * WW + xi0) * 8);
  const float4* p01 = (const float4*)(sg + ((long)yi0 * WW + xi1) * 8);
  const float4* p10 = (const float4*)(sg + ((long)yi1 * WW + xi0) * 8);
  const float4* p11 = (const float4*)(sg + ((long)yi1 * WW + xi1) * 8);
  float4 a00 = p00[0], b00 = p00[1];
  float4 a01 = p01[0], b01 = p01[1];
  float4 a10 = p10[0], b10 = p10[1];
  float4 a11 = p11[0], b11 = p11[1];
  sv[0] = w00 * a00.x + w01 * a01.x + w10 * a10.x + w11 * a11.x;
  sv[1] = w00 * a00.y + w01 * a01.y + w10 * a10.y + w11 * a11.y;
  sv[2] = w00 * a00.z + w01 * a01.z + w10 * a10.z + w11 * a11.z;
  sv[3] = w00 * a00.w + w01 * a01.w + w10 * a10.w + w11 * a11.w;
  sv[4] = w00 * b00.x + w01 * b01.x + w10 * b10.x + w11 * b11.x;
  sv[5] = w00 * b00.y + w01 * b01.y + w10 * b10.y + w11 * b11.y;
  sv[6] = w00 * b00.z + w01 * b01.z + w10 * b10.z + w11 * b11.z;
  sv[7] = w00 * b00.w + w01 * b01.w + w10 * b10.w + w11 * b11.w;
}

// ---------------------------------------------------------------------------
// Deform as split-fp16 MFMA implicit GEMM with fused bilinear sampling.
// v2: offsets staged in LDS up front; img-major block swizzle for XCD/L2.
// ---------------------------------------------------------------------------
__global__ __launch_bounds__(256) void deform_mfma_k(
    const float* __restrict__ srcg, const float* __restrict__ off,
    const unsigned short* __restrict__ wh, const unsigned short* __restrict__ wl,
    float* __restrict__ out, int img0, int cmask, int cshift)
{
  __shared__ __align__(16) float s_off[9216];           // [144][64 px]
  __shared__ __align__(16) unsigned short s_bh[4096];
  __shared__ __align__(16) unsigned short s_bl[4096];
  const int tid = threadIdx.x;
  const int lane = tid & 63;
  const int wv = tid >> 6;
  const int m16 = lane & 15, q = lane >> 4;
  const int bid = blockIdx.x;
  const int iz = bid & cmask;
  const int tile = bid >> cshift;
  const int img = img0 + iz;
  const int tp0 = tile * 64;
  const int pl = wv * 16 + m16;          // local px 0..63
  const int p = tp0 + pl;
  const float fy = (float)(p >> 7), fx = (float)(p & 127);
  const int rot = 8 * (m16 & 7);

  {
    const float* ob = off + (long)iz * 144 * HWX + tp0;
    for (int t = tid; t < 2304; t += 256) {            // 144 ch x 16 float4
      int c = t >> 4, j = t & 15;
      *(float4*)(s_off + c * 64 + 4 * j) =
          *(const float4*)(ob + (long)c * HWX + 4 * j);
    }
  }

  f32x4 acc[4];
#pragma unroll
  for (int nt = 0; nt < 4; ++nt)
#pragma unroll
    for (int i = 0; i < 4; ++i) acc[nt][i] = 0.f;

  for (int k2 = 0; k2 < 9; ++k2) {
    __syncthreads();
    for (int t = tid; t < 512; t += 256) {
      int o = t >> 3, j = t & 7;
      int d = o * 64 + ((8 * j + 8 * (o & 7)) & 63);
      long so = ((long)k2 * 64 + o) * 64 + 8 * j;
      *(uint4*)(s_bh + d) = *(const uint4*)(wh + so);
      *(uint4*)(s_bl + d) = *(const uint4*)(wl + so);
    }
    __syncthreads();
    const float kyf = (float)(k2 / 3 - 1), kxf = (float)(k2 % 3 - 1);
#pragma unroll
    for (int s = 0; s < 2; ++s) {
      const int g = 4 * s + q;
      float dyv = s_off[(g * 18 + 2 * k2) * 64 + pl];
      float dxv = s_off[(g * 18 + 2 * k2 + 1) * 64 + pl];
      float sv[8];
      bilin8(srcg + (long)(img * 8 + g) * HWX * 8,
             dyv + fy + kyf, dxv + fx + kxf, sv);
      f16x8 ah, al;
#pragma unroll
      for (int j = 0; j < 8; ++j) {
        _Float16 h = (_Float16)sv[j];
        _Float16 l = (_Float16)(sv[j] - (float)h);
        ah[j] = h; al[j] = l;
      }
      const int roff = (32 * s + 8 * q + rot) & 63;
#pragma unroll
      for (int nt = 0; nt < 4; ++nt) {
        int o = nt * 16 + m16;
        f16x8 bh = *(const f16x8*)(s_bh + o * 64 + roff);
        f16x8 bl = *(const f16x8*)(s_bl + o * 64 + roff);
        acc[nt] = __builtin_amdgcn_mfma_f32_16x16x32_f16(ah, bl, acc[nt], 0, 0, 0);
        acc[nt] = __builtin_amdgcn_mfma_f32_16x16x32_f16(al, bh, acc[nt], 0, 0, 0);
        acc[nt] = __builtin_amdgcn_mfma_f32_16x16x32_f16(ah, bh, acc[nt], 0, 0, 0);
      }
    }
  }

  const long pb = tp0 + wv * 16 + q * 4;
#pragma unroll
  for (int nt = 0; nt < 4; ++nt) {
    int oc = nt * 16 + m16;
    float4 v;
    v.x = acc[nt][0]; v.y = acc[nt][1]; v.z = acc[nt][2]; v.w = acc[nt][3];
    *(float4*)(out + ((long)img * 64 + oc) * HWX + pb) = v;
  }
}

__global__ __launch_bounds__(256) void assemble_k(
    const float* __restrict__ x, const float* __restrict__ im,
    const float* __restrict__ out0, const float* __restrict__ fea,
    float* __restrict__ out)
{
  int idx = blockIdx.x * 256 + threadIdx.x;
  if (idx < 491520) {
    int within = idx % 49152;
    int n = (idx / 49152) % 5;
    int b = idx / (49152 * 5);
    float v;
    if (n == 2) v = x[(b * 5 + 2) * 49152 + within];
    else {
      int j = b * 4 + (n < 2 ? n : n - 1);
      v = im[j * 49152 + within];
    }
    out[idx] = v;
  } else if (idx < 10977280) {
    int idx2 = idx - 491520;
    int within = idx2 % 1048576;
    int n = (idx2 / 1048576) % 5;
    int b = idx2 / (1048576 * 5);
    float v;
    if (n == 2) v = out0[(b * 5 + 2) * 1048576 + within];
    else {
      int j = b * 4 + (n < 2 ? n : n - 1);
      v = fea[j * 1048576 + within];
    }
    out[idx] = v;
  }
}

// ---------------------------------------------------------------------------
extern "C" void kernel_launch(void* const* d_in, const int* in_sizes, int n_in,
                              void* d_out, int out_size, void* d_ws, size_t ws_size,
                              hipStream_t stream) {
  const float* x   = (const float*)d_in[0];
  const float* cfw = (const float*)d_in[1];
  const float* cfb = (const float*)d_in[2];
  const float* rw1 = (const float*)d_in[3];
  const float* rb1 = (const float*)d_in[4];
  const float* rw2 = (const float*)d_in[5];
  const float* rb2 = (const float*)d_in[6];
  const float* crw = (const float*)d_in[7];
  const float* crb = (const float*)d_in[8];
  const float* ofw = (const float*)d_in[9];
  const float* ofb = (const float*)d_in[10];
  const float* dcw = (const float*)d_in[11];
  const float* rcw = (const float*)d_in[12];
  const float* rcb = (const float*)d_in[13];
  float* out = (float*)d_out;

  // conv weight arenas (hi|lo), then deform weight arenas (hi|lo)
  unsigned short* WH = (unsigned short*)d_ws;
  unsigned short* WL = WH + 774144;
  unsigned short* DH = WH + 1548288;
  unsigned short* DL = DH + 147456;
  const long W_res1 = 0, W_res2 = 184320, W_cr = 368640, W_off = 442368;

  float* A = (float*)d_ws + 921600;                  // (10,64,HW)
  float* C = A + 10485760;                           // fea ping (8,64,HW)
  float* D = C + 8388608;                            // grouped / im
  float* F = D + 8388608;                            // fea3
  float* OFF = F + 8388608;                          // offsets (chunk,144,HW)
  float* r = C;
  float* im = D;

  const size_t fixedF = 921600UL + 10485760UL + 3UL * 8388608UL;
  int chunk = 8;
  while (chunk > 1 && (fixedF + (size_t)chunk * 2359296UL) * sizeof(float) > ws_size)
    chunk >>= 1;
  int cshift = (chunk == 8) ? 3 : (chunk == 4) ? 2 : (chunk == 2) ? 1 : 0;

  dim3 blk(256);

  // weight prep
  wprep_k<<<720, blk, 0, stream>>>(rw1, WH + W_res1, WL + W_res1, 64, 64, 5);
  wprep_k<<<720, blk, 0, stream>>>(rw2, WH + W_res2, WL + W_res2, 64, 64, 5);
  wprep_k<<<288, blk, 0, stream>>>(crw, WH + W_cr, WL + W_cr, 64, 128, 1);
  wprep_k<<<1296, blk, 0, stream>>>(ofw, WH + W_off, WL + W_off, 144, 64, 4);
  dwprep_k<<<576, blk, 0, stream>>>(dcw, DH, DL);

  // conv_first + ReLU : x (10,3,HW) -> A (10,64,HW)   [VALU fp32, CIN=3]
  conv3x3_k<3, 3, 16, true, false><<<dim3(4, 4, 40), blk, 0, stream>>>(
      x, cfw, cfb, nullptr, A, 64, 4, 0, 0);

  // 5 residual blocks (split-fp16 MFMA, full 64 oc per block)
  for (int i = 0; i < 5; ++i) {
    conv_mfma_k<2, 4, true, false, false><<<dim3(4, 16, 10), blk, 0, stream>>>(
        A, WH + W_res1 + (long)i * 36864, WL + W_res1 + (long)i * 36864,
        rb1 + i * 64, nullptr, r, 64, 1, 0, 0);
    conv_mfma_k<2, 4, false, true, false><<<dim3(4, 16, 10), blk, 0, stream>>>(
        r, WH + W_res2 + (long)i * 36864, WL + W_res2 + (long)i * 36864,
        rb2 + i * 64, A, A, 64, 1, 0, 0);
  }

  // cr conv, fused concat(ref,supp): A -> C (fea0)
  conv_mfma_k<4, 4, false, false, true><<<dim3(4, 16, 8), blk, 0, stream>>>(
      A, WH + W_cr, WL + W_cr, crb, nullptr, C, 64, 1, 0, 0);

  // offset conv (split-fp16 MFMA, 144ch = 3x48) + deform (MFMA), chunked
  auto off_deform = [&](const float* fea_in, const float* grouped,
                        int layer, float* outp) {
    for (int i0 = 0; i0 < 8; i0 += chunk) {
      conv_mfma_k<2, 3, false, false, false>
          <<<dim3(4, 16, chunk * 3), blk, 0, stream>>>(
              fea_in, WH + W_off + (long)layer * 82944,
              WL + W_off + (long)layer * 82944, ofb + layer * 144,
              nullptr, OFF, 144, 3, i0, 0);
      deform_mfma_k<<<dim3(256 * chunk), blk, 0, stream>>>(
          grouped, OFF, DH + (long)layer * 36864, DL + (long)layer * 36864,
          outp, i0, chunk - 1, cshift);
    }
  };

  // layer 0: fea1 = deform(fea0, conv(fea0))        C -> C
  regroup_k<<<32768, blk, 0, stream>>>(C, D, 0);
  off_deform(C, D, 0, C);

  // layer 1: fea2 = deform(fea1, conv(fea1))        C -> C
  regroup_k<<<32768, blk, 0, stream>>>(C, D, 0);
  off_deform(C, D, 1, C);

  // layer 2: fea3 = deform(supp, conv(fea2))        (A supp, C) -> F
  regroup_k<<<32768, blk, 0, stream>>>(A, D, 1);
  off_deform(C, D, 2, F);

  // layer 3: aligned = deform(fea3, conv(fea3))     F -> C
  regroup_k<<<32768, blk, 0, stream>>>(F, D, 0);
  off_deform(F, D, 3, C);

  // recon conv: aligned -> im (8,3,HW)   [VALU fp32, Cout=3]
  conv3x3_k<64, 8, 4, false, false><<<dim3(4, 4, 8), blk, 0, stream>>>(
      C, rcw, rcb, nullptr, im, 3, 1, 0, 0);

  // assemble outputs
  assemble_k<<<42880, blk, 0, stream>>>(x, im, A, F, out);
}

// Round 8
// 1961.675 us; speedup vs baseline: 2.8520x; 1.0221x over previous
//
#include <hip/hip_runtime.h>

#define HH 128
#define WW 128
#define HWX (HH*WW)

using f32x4 = __attribute__((ext_vector_type(4))) float;
using f16x8 = __attribute__((ext_vector_type(8))) _Float16;

__device__ __forceinline__ unsigned short f16bits(_Float16 h) {
  union { _Float16 f; unsigned short u; } v; v.f = h; return v.u;
}

// chunk swizzle: position pos (64B row of 32 f16), chunk q (16B of 8 f16)
__device__ __forceinline__ int swz(int pos, int q) {
  return pos * 32 + (((q + pos + (pos >> 2)) & 3) << 3);
}

// ---------------------------------------------------------------------------
// Weight prep: OIHW fp32 -> [layer][kpos][O][I] split-fp16 (hi + lo arenas)
// ---------------------------------------------------------------------------
__global__ __launch_bounds__(256) void wprep_k(
    const float* __restrict__ src, unsigned short* __restrict__ dhi,
    unsigned short* __restrict__ dlo, int O, int I, int L)
{
  int idx = blockIdx.x * 256 + threadIdx.x;
  int tot = L * O * I * 9;
  if (idx >= tot) return;
  int per = O * I * 9;
  int layer = idx / per;
  int r = idx - layer * per;
  int o = r / (I * 9);
  int r2 = r - o * (I * 9);
  int i = r2 / 9, k = r2 - i * 9;
  float v = src[idx];
  _Float16 h = (_Float16)v;
  _Float16 l = (_Float16)(v - (float)h);
  long di = (long)layer * per + ((long)k * O + o) * I + i;
  dhi[di] = f16bits(h);
  dlo[di] = f16bits(l);
}

// ---------------------------------------------------------------------------
// Deform weight prep: [L][O=64][I=64][9] fp32 -> [L][k2][o][r=I] split-fp16
// ---------------------------------------------------------------------------
__global__ __launch_bounds__(256) void dwprep_k(
    const float* __restrict__ src, unsigned short* __restrict__ dhi,
    unsigned short* __restrict__ dlo)
{
  int idx = blockIdx.x * 256 + threadIdx.x;      // 4*36864 = 147456
  if (idx >= 147456) return;
  int l = idx / 36864;
  int rem = idx - l * 36864;
  int o = rem / 576;
  int rem2 = rem - o * 576;
  int r = rem2 / 9, k2 = rem2 - r * 9;
  float v = src[idx];
  _Float16 h = (_Float16)v;
  _Float16 lo = (_Float16)(v - (float)h);
  long di = (((long)l * 9 + k2) * 64 + o) * 64 + r;
  dhi[di] = f16bits(h);
  dlo[di] = f16bits(lo);
}

// ---------------------------------------------------------------------------
// Split-fp16 MFMA implicit-GEMM 3x3 SAME conv. Block 256 thr = 4 waves.
// Weights staged per-kp, double-buffered.
// ---------------------------------------------------------------------------
template<int CBLK, int NFRAG, bool RELU, bool ADD, bool CRMODE>
__global__ __launch_bounds__(256, 2) void conv_mfma_k(
    const float* __restrict__ in, const unsigned short* __restrict__ whi,
    const unsigned short* __restrict__ wlo,
    const float* __restrict__ bias, const float* __restrict__ res,
    float* __restrict__ out, int Cout, int nslice, int img_in0, int img_out0)
{
  constexpr int CIN = CBLK * 32;
  constexpr int OCB = NFRAG * 16;
  constexpr int SLAB = OCB * 32;               // ushorts per (buf,half)
  __shared__ __align__(16) unsigned short s_in[2 * 10880];   // 10x34 halo hi|lo
  __shared__ __align__(16) unsigned short s_w[2][2 * SLAB];  // [buf][hi|lo]

  const int tid = threadIdx.x;
  const int lane = tid & 63;
  const int wv = tid >> 6;
  const int m16 = lane & 15, q = lane >> 4;
  const int iz = blockIdx.z / nslice, slice = blockIdx.z % nslice;
  const int oc_blk0 = slice * OCB;
  const int x0 = blockIdx.x * 32, y0 = blockIdx.y * 8;

  f32x4 acc[4][NFRAG];
#pragma unroll
  for (int mt = 0; mt < 4; ++mt)
#pragma unroll
    for (int nt = 0; nt < NFRAG; ++nt)
#pragma unroll
      for (int i = 0; i < 4; ++i) acc[mt][nt][i] = 0.f;

  int bb = 0, nn = 0;
  const float* inb = in;
  if (CRMODE) {
    int j = img_in0 + iz;
    bb = j >> 2;
    int ns = j & 3;
    nn = ns < 2 ? ns : ns + 1;
  } else {
    inb = in + (long)(img_in0 + iz) * CIN * HWX;
  }

  for (int cb = 0; cb < CBLK; ++cb) {
    const int c0 = cb * 32;
    // ---- stage input tile: fp32 -> (hi,lo) fp16, channels-last, swizzled ----
    for (int t = tid; t < 1360; t += 256) {
      int qq = t / 340, pos = t - qq * 340;
      int iy = pos / 34, ix = pos - iy * 34;
      int gy = y0 + iy - 1, gx = x0 + ix - 1;
      bool inr = (gy >= 0 && gy < HH && gx >= 0 && gx < WW);
      const float* src;
      if (CRMODE) {
        int ch = c0 + qq * 8;
        int simg = (ch < 64) ? (bb * 5 + 2) : (bb * 5 + nn);
        src = in + ((long)simg * 64 + (ch & 63)) * HWX + gy * WW + gx;
      } else {
        src = inb + (long)(c0 + qq * 8) * HWX + gy * WW + gx;
      }
      unsigned hi4[4], lo4[4];
#pragma unroll
      for (int j2 = 0; j2 < 4; ++j2) {
        unsigned short hs[2], ls[2];
#pragma unroll
        for (int j = 0; j < 2; ++j) {
          float v = inr ? src[(long)(j2 * 2 + j) * HWX] : 0.f;
          _Float16 h = (_Float16)v;
          _Float16 l = (_Float16)(v - (float)h);
          hs[j] = f16bits(h); ls[j] = f16bits(l);
        }
        hi4[j2] = (unsigned)hs[0] | ((unsigned)hs[1] << 16);
        lo4[j2] = (unsigned)ls[0] | ((unsigned)ls[1] << 16);
      }
      *(uint4*)(s_in + swz(pos, qq)) = make_uint4(hi4[0], hi4[1], hi4[2], hi4[3]);
      *(uint4*)(s_in + 10880 + swz(pos, qq)) =
          make_uint4(lo4[0], lo4[1], lo4[2], lo4[3]);
    }
    // ---- stage kp=0 weight slab into buf 0 ----
    for (int t = tid; t < OCB * 4; t += 256) {
      int qq = t & 3, ocl = t >> 2;
      long so = ((long)0 * Cout + oc_blk0 + ocl) * CIN + c0 + qq * 8;
      *(uint4*)(s_w[0] + swz(ocl, qq)) = *(const uint4*)(whi + so);
      *(uint4*)(s_w[0] + SLAB + swz(ocl, qq)) = *(const uint4*)(wlo + so);
    }
    __syncthreads();

#pragma unroll
    for (int kp = 0; kp < 9; ++kp) {
      if (kp < 8) {
        const int buf = (kp + 1) & 1;
        for (int t = tid; t < OCB * 4; t += 256) {
          int qq = t & 3, ocl = t >> 2;
          long so = ((long)(kp + 1) * Cout + oc_blk0 + ocl) * CIN + c0 + qq * 8;
          *(uint4*)(s_w[buf] + swz(ocl, qq)) = *(const uint4*)(whi + so);
          *(uint4*)(s_w[buf] + SLAB + swz(ocl, qq)) = *(const uint4*)(wlo + so);
        }
      }
      const unsigned short* wb = s_w[kp & 1];
      const int dy = kp / 3, dx = kp - dy * 3;
      f16x8 bhi[NFRAG], blo[NFRAG];
#pragma unroll
      for (int nt = 0; nt < NFRAG; ++nt) {
        int pw = nt * 16 + m16;
        bhi[nt] = *(const f16x8*)(wb + swz(pw, q));
        blo[nt] = *(const f16x8*)(wb + SLAB + swz(pw, q));
      }
#pragma unroll
      for (int mt = 0; mt < 4; ++mt) {
        int r = 2 * wv + (mt >> 1), h = mt & 1;
        int pos = (r + dy) * 34 + h * 16 + m16 + dx;
        f16x8 ahi = *(const f16x8*)(s_in + swz(pos, q));
        f16x8 alo = *(const f16x8*)(s_in + 10880 + swz(pos, q));
#pragma unroll
        for (int nt = 0; nt < NFRAG; ++nt) {
          acc[mt][nt] = __builtin_amdgcn_mfma_f32_16x16x32_f16(
              ahi, blo[nt], acc[mt][nt], 0, 0, 0);
          acc[mt][nt] = __builtin_amdgcn_mfma_f32_16x16x32_f16(
              alo, bhi[nt], acc[mt][nt], 0, 0, 0);
          acc[mt][nt] = __builtin_amdgcn_mfma_f32_16x16x32_f16(
              ahi, bhi[nt], acc[mt][nt], 0, 0, 0);
        }
      }
      __syncthreads();
    }
  }

  const int img_o = img_out0 + iz;
#pragma unroll
  for (int mt = 0; mt < 4; ++mt) {
    int r = 2 * wv + (mt >> 1), h = mt & 1;
    int y = y0 + r;
    int xb = x0 + h * 16 + q * 4;
#pragma unroll
    for (int nt = 0; nt < NFRAG; ++nt) {
      int oc = oc_blk0 + nt * 16 + m16;
      if (oc < Cout) {
        float bsv = bias[oc];
        long base = ((long)img_o * Cout + oc) * HWX + (long)y * WW + xb;
#pragma unroll
        for (int i = 0; i < 4; ++i) {
          float v = acc[mt][nt][i] + bsv;
          if (RELU) v = fmaxf(v, 0.f);
          if (ADD) v += res[base + i];
          out[base + i] = v;
        }
      }
    }
  }
}

// ---------------------------------------------------------------------------
// Fallback VALU conv (conv_first CIN=3 and recon Cout=3).
// ---------------------------------------------------------------------------
template<int CIN, int CK, int OCB, bool RELU, bool ADD>
__global__ __launch_bounds__(256) void conv3x3_k(
    const float* __restrict__ in, const float* __restrict__ wgt,
    const float* __restrict__ bias, const float* __restrict__ res,
    float* __restrict__ out, int Cout, int nslice, int img_in0, int img_out0)
{
  __shared__ __align__(16) float s_in[CK][34][34];
  __shared__ __align__(16) float s_w[CK * 9 * OCB];

  const int tid = threadIdx.x;
  const int tx = tid & 31;
  const int ty = tid >> 5;
  const int iz = blockIdx.z / nslice;
  const int slice = blockIdx.z % nslice;
  const int oc0 = slice * OCB;
  const int x0 = blockIdx.x * 32;
  const int y0 = blockIdx.y * 32;

  float acc[4][OCB];
#pragma unroll
  for (int r = 0; r < 4; ++r)
#pragma unroll
    for (int o = 0; o < OCB; ++o) acc[r][o] = 0.f;

  const float* inb = in + (long)(img_in0 + iz) * CIN * HWX;

  for (int c0 = 0; c0 < CIN; c0 += CK) {
    __syncthreads();
    for (int idx = tid; idx < CK * 34 * 34; idx += 256) {
      int c = idx / 1156;
      int rem = idx % 1156;
      int iy = rem / 34, ix = rem % 34;
      int gy = y0 + iy - 1, gx = x0 + ix - 1;
      float v = 0.f;
      if (gy >= 0 && gy < HH && gx >= 0 && gx < WW)
        v = inb[(long)(c0 + c) * HWX + gy * WW + gx];
      s_in[c][iy][ix] = v;
    }
    for (int idx = tid; idx < CK * 9 * OCB; idx += 256) {
      int oc = idx % OCB;
      int ck = idx / OCB;
      int c = ck / 9, k = ck % 9;
      int ocg = oc0 + oc;
      float v = 0.f;
      if (ocg < Cout) v = wgt[((long)ocg * CIN + c0 + c) * 9 + k];
      s_w[idx] = v;
    }
    __syncthreads();

    for (int c = 0; c < CK; ++c) {
#pragma unroll
      for (int k = 0; k < 9; ++k) {
        const int ky = k / 3, kx = k % 3;
        float v0 = s_in[c][ty + ky][tx + kx];
        float v1 = s_in[c][ty + 8 + ky][tx + kx];
        float v2 = s_in[c][ty + 16 + ky][tx + kx];
        float v3 = s_in[c][ty + 24 + ky][tx + kx];
        const float4* wp = (const float4*)&s_w[(c * 9 + k) * OCB];
#pragma unroll
        for (int o4 = 0; o4 < OCB / 4; ++o4) {
          float4 w4 = wp[o4];
          acc[0][o4 * 4 + 0] += v0 * w4.x; acc[0][o4 * 4 + 1] += v0 * w4.y;
          acc[0][o4 * 4 + 2] += v0 * w4.z; acc[0][o4 * 4 + 3] += v0 * w4.w;
          acc[1][o4 * 4 + 0] += v1 * w4.x; acc[1][o4 * 4 + 1] += v1 * w4.y;
          acc[1][o4 * 4 + 2] += v1 * w4.z; acc[1][o4 * 4 + 3] += v1 * w4.w;
          acc[2][o4 * 4 + 0] += v2 * w4.x; acc[2][o4 * 4 + 1] += v2 * w4.y;
          acc[2][o4 * 4 + 2] += v2 * w4.z; acc[2][o4 * 4 + 3] += v2 * w4.w;
          acc[3][o4 * 4 + 0] += v3 * w4.x; acc[3][o4 * 4 + 1] += v3 * w4.y;
          acc[3][o4 * 4 + 2] += v3 * w4.z; acc[3][o4 * 4 + 3] += v3 * w4.w;
        }
      }
    }
  }

#pragma unroll
  for (int o = 0; o < OCB; ++o) {
    int ocg = oc0 + o;
    if (ocg < Cout) {
      float b = bias ? bias[ocg] : 0.f;
      long base = ((long)(img_out0 + iz) * Cout + ocg) * HWX;
#pragma unroll
      for (int r = 0; r < 4; ++r) {
        int y = y0 + ty + 8 * r;
        float v = acc[r][o] + b;
        if (RELU) v = fmaxf(v, 0.f);
        long ia = base + (long)y * WW + x0 + tx;
        if (ADD) v += res[ia];
        out[ia] = v;
      }
    }
  }
}

// ---------------------------------------------------------------------------
__global__ __launch_bounds__(256) void regroup_k(
    const float* __restrict__ src, float* __restrict__ dst, int supp_mode)
{
  int idx = blockIdx.x * 256 + threadIdx.x;
  int c = idx & 7;
  int p = (idx >> 3) & 16383;
  int g = (idx >> 17) & 7;
  int img = idx >> 20;
  int simg = img;
  if (supp_mode) {
    int b = img >> 2, ns = img & 3;
    simg = b * 5 + (ns < 2 ? ns : ns + 1);
  }
  dst[idx] = src[((simg * 64 + g * 8 + c) * HWX) + p];
}

// ---------------------------------------------------------------------------
// Deform v3: split-fp16 MFMA implicit GEMM, fused bilinear sampling,
// register-level software pipeline:
//   - 3-deep offset prefetch ring (global, each OFF element read once)
//   - 1-deep corner prefetch (8x float4 issued one step ahead of use)
//   - double-buffered weight slabs (stage k2+1 during k2; 1 barrier/k2)
// LDS = 32 KB. img-major block swizzle for XCD/L2 locality retained.
// ---------------------------------------------------------------------------
__global__ __launch_bounds__(256) void deform_mfma_k(
    const float* __restrict__ srcg, const float* __restrict__ off,
    const unsigned short* __restrict__ wh, const unsigned short* __restrict__ wl,
    float* __restrict__ out, int img0, int cmask, int cshift)
{
  __shared__ __align__(16) unsigned short s_w[2][2 * 4096];
  const int tid = threadIdx.x;
  const int lane = tid & 63;
  const int wv = tid >> 6;
  const int m16 = lane & 15, q = lane >> 4;
  const int bid = blockIdx.x;
  const int iz = bid & cmask;
  const int tile = bid >> cshift;
  const int img = img0 + iz;
  const int tp0 = tile * 64;
  const int p = tp0 + wv * 16 + m16;
  const float fy = (float)(p >> 7), fx = (float)(p & 127);
  const int rot = 8 * (m16 & 7);

  const float* offb = off + (long)iz * 144 * HWX + p;
  const float* sgq[2];
  sgq[0] = srcg + (long)(img * 8 + q) * HWX * 8;        // s=0: g=q
  sgq[1] = srcg + (long)(img * 8 + 4 + q) * HWX * 8;    // s=1: g=4+q

  float dyr[3], dxr[3];
  float pyr[2], pxr[2];
  float4 cr[2][8];

#define LOAD_OFF(T, SLOT) { \
    const float* ob_ = offb + ((long)(4 * ((T) & 1) + q) * 18 + 2 * ((T) >> 1)) * HWX; \
    dyr[SLOT] = ob_[0]; dxr[SLOT] = ob_[HWX]; }

#define ISSUE(T, SLOT, OS) { \
    const int k2_ = (T) >> 1; \
    float py_ = dyr[OS] + fy + (float)(k2_ / 3 - 1); \
    float px_ = dxr[OS] + fx + (float)(k2_ % 3 - 1); \
    pyr[SLOT] = py_; pxr[SLOT] = px_; \
    float y0f_ = floorf(py_), x0f_ = floorf(px_); \
    int yi0_ = (int)fminf(fmaxf(y0f_, 0.f), 127.f); \
    int yi1_ = (int)fminf(fmaxf(y0f_ + 1.f, 0.f), 127.f); \
    int xi0_ = (int)fminf(fmaxf(x0f_, 0.f), 127.f); \
    int xi1_ = (int)fminf(fmaxf(x0f_ + 1.f, 0.f), 127.f); \
    const float* sg_ = sgq[(T) & 1]; \
    const float4* p00_ = (const float4*)(sg_ + ((long)yi0_ * WW + xi0_) * 8); \
    const float4* p01_ = (const float4*)(sg_ + ((long)yi0_ * WW + xi1_) * 8); \
    const float4* p10_ = (const float4*)(sg_ + ((long)yi1_ * WW + xi0_) * 8); \
    const float4* p11_ = (const float4*)(sg_ + ((long)yi1_ * WW + xi1_) * 8); \
    cr[SLOT][0] = p00_[0]; cr[SLOT][1] = p00_[1]; \
    cr[SLOT][2] = p01_[0]; cr[SLOT][3] = p01_[1]; \
    cr[SLOT][4] = p10_[0]; cr[SLOT][5] = p10_[1]; \
    cr[SLOT][6] = p11_[0]; cr[SLOT][7] = p11_[1]; }

#define STAGE(K2) { \
    const int buf_ = (K2) & 1; \
    for (int t2 = tid; t2 < 512; t2 += 256) { \
      int o_ = t2 >> 3, j_ = t2 & 7; \
      int d_ = o_ * 64 + ((8 * j_ + 8 * (o_ & 7)) & 63); \
      long so_ = ((long)(K2) * 64 + o_) * 64 + 8 * j_; \
      *(uint4*)(s_w[buf_] + d_) = *(const uint4*)(wh + so_); \
      *(uint4*)(s_w[buf_] + 4096 + d_) = *(const uint4*)(wl + so_); \
    } }

#define PROCESS(T, SLOT) { \
    float py_ = pyr[SLOT], px_ = pxr[SLOT]; \
    float y0f_ = floorf(py_), x0f_ = floorf(px_); \
    float wy_ = py_ - y0f_, wx_ = px_ - x0f_; \
    float my0 = (y0f_ >= 0.f && y0f_ <= 127.f) ? 1.f : 0.f; \
    float my1 = (y0f_ >= -1.f && y0f_ <= 126.f) ? 1.f : 0.f; \
    float mx0 = (x0f_ >= 0.f && x0f_ <= 127.f) ? 1.f : 0.f; \
    float mx1 = (x0f_ >= -1.f && x0f_ <= 126.f) ? 1.f : 0.f; \
    float w00 = (1.f - wy_) * (1.f - wx_) * my0 * mx0; \
    float w01 = (1.f - wy_) * wx_ * my0 * mx1; \
    float w10 = wy_ * (1.f - wx_) * my1 * mx0; \
    float w11 = wy_ * wx_ * my1 * mx1; \
    f16x8 ah, al; \
    _Pragma("unroll") \
    for (int j = 0; j < 4; ++j) { \
      float v0 = w00 * ((const float*)&cr[SLOT][0])[j] + w01 * ((const float*)&cr[SLOT][2])[j] \
               + w10 * ((const float*)&cr[SLOT][4])[j] + w11 * ((const float*)&cr[SLOT][6])[j]; \
      float v1 = w00 * ((const float*)&cr[SLOT][1])[j] + w01 * ((const float*)&cr[SLOT][3])[j] \
               + w10 * ((const float*)&cr[SLOT][5])[j] + w11 * ((const float*)&cr[SLOT][7])[j]; \
      _Float16 h0 = (_Float16)v0; ah[j] = h0; al[j] = (_Float16)(v0 - (float)h0); \
      _Float16 h1 = (_Float16)v1; ah[4 + j] = h1; al[4 + j] = (_Float16)(v1 - (float)h1); \
    } \
    const unsigned short* wb_ = s_w[((T) >> 1) & 1]; \
    const int roff_ = (32 * ((T) & 1) + 8 * q + rot) & 63; \
    _Pragma("unroll") \
    for (int nt = 0; nt < 4; ++nt) { \
      int o_ = nt * 16 + m16; \
      f16x8 bh = *(const f16x8*)(wb_ + o_ * 64 + roff_); \
      f16x8 bl = *(const f16x8*)(wb_ + 4096 + o_ * 64 + roff_); \
      acc[nt] = __builtin_amdgcn_mfma_f32_16x16x32_f16(ah, bl, acc[nt], 0, 0, 0); \
      acc[nt] = __builtin_amdgcn_mfma_f32_16x16x32_f16(al, bh, acc[nt], 0, 0, 0); \
      acc[nt] = __builtin_amdgcn_mfma_f32_16x16x32_f16(ah, bh, acc[nt], 0, 0, 0); \
    } }

  f32x4 acc[4];
#pragma unroll
  for (int nt = 0; nt < 4; ++nt)
#pragma unroll
    for (int i = 0; i < 4; ++i) acc[nt][i] = 0.f;

  // prologue: fill offset ring, issue corners for step 0, stage slab 0
  LOAD_OFF(0, 0);
  LOAD_OFF(1, 1);
  ISSUE(0, 0, 0);
  LOAD_OFF(2, 2);
  STAGE(0);
  __syncthreads();

#pragma unroll
  for (int k2 = 0; k2 < 9; ++k2) {
    if (k2 < 8) STAGE(k2 + 1);
#pragma unroll
    for (int s = 0; s < 2; ++s) {
      const int t = 2 * k2 + s;
      if (t < 17) ISSUE(t + 1, (t + 1) & 1, (t + 1) % 3);
      if (t < 15) LOAD_OFF(t + 3, (t + 3) % 3);
      PROCESS(t, t & 1);
    }
    __syncthreads();
  }

#undef LOAD_OFF
#undef ISSUE
#undef STAGE
#undef PROCESS

  const long pb = tp0 + wv * 16 + q * 4;
#pragma unroll
  for (int nt = 0; nt < 4; ++nt) {
    int oc = nt * 16 + m16;
    float4 v;
    v.x = acc[nt][0]; v.y = acc[nt][1]; v.z = acc[nt][2]; v.w = acc[nt][3];
    *(float4*)(out + ((long)img * 64 + oc) * HWX + pb) = v;
  }
}

__global__ __launch_bounds__(256) void assemble_k(
    const float* __restrict__ x, const float* __restrict__ im,
    const float* __restrict__ out0, const float* __restrict__ fea,
    float* __restrict__ out)
{
  int idx = blockIdx.x * 256 + threadIdx.x;
  if (idx < 491520) {
    int within = idx % 49152;
    int n = (idx / 49152) % 5;
    int b = idx / (49152 * 5);
    float v;
    if (n == 2) v = x[(b * 5 + 2) * 49152 + within];
    else {
      int j = b * 4 + (n < 2 ? n : n - 1);
      v = im[j * 49152 + within];
    }
    out[idx] = v;
  } else if (idx < 10977280) {
    int idx2 = idx - 491520;
    int within = idx2 % 1048576;
    int n = (idx2 / 1048576) % 5;
    int b = idx2 / (1048576 * 5);
    float v;
    if (n == 2) v = out0[(b * 5 + 2) * 1048576 + within];
    else {
      int j = b * 4 + (n < 2 ? n : n - 1);
      v = fea[j * 1048576 + within];
    }
    out[idx] = v;
  }
}

// ---------------------------------------------------------------------------
extern "C" void kernel_launch(void* const* d_in, const int* in_sizes, int n_in,
                              void* d_out, int out_size, void* d_ws, size_t ws_size,
                              hipStream_t stream) {
  const float* x   = (const float*)d_in[0];
  const float* cfw = (const float*)d_in[1];
  const float* cfb = (const float*)d_in[2];
  const float* rw1 = (const float*)d_in[3];
  const float* rb1 = (const float*)d_in[4];
  const float* rw2 = (const float*)d_in[5];
  const float* rb2 = (const float*)d_in[6];
  const float* crw = (const float*)d_in[7];
  const float* crb = (const float*)d_in[8];
  const float* ofw = (const float*)d_in[9];
  const float* ofb = (const float*)d_in[10];
  const float* dcw = (const float*)d_in[11];
  const float* rcw = (const float*)d_in[12];
  const float* rcb = (const float*)d_in[13];
  float* out = (float*)d_out;

  // conv weight arenas (hi|lo), then deform weight arenas (hi|lo)
  unsigned short* WH = (unsigned short*)d_ws;
  unsigned short* WL = WH + 774144;
  unsigned short* DH = WH + 1548288;
  unsigned short* DL = DH + 147456;
  const long W_res1 = 0, W_res2 = 184320, W_cr = 368640, W_off = 442368;

  float* A = (float*)d_ws + 921600;                  // (10,64,HW)
  float* C = A + 10485760;                           // fea ping (8,64,HW)
  float* D = C + 8388608;                            // grouped / im
  float* F = D + 8388608;                            // fea3
  float* OFF = F + 8388608;                          // offsets (chunk,144,HW)
  float* r = C;
  float* im = D;

  const size_t fixedF = 921600UL + 10485760UL + 3UL * 8388608UL;
  int chunk = 8;
  while (chunk > 1 && (fixedF + (size_t)chunk * 2359296UL) * sizeof(float) > ws_size)
    chunk >>= 1;
  int cshift = (chunk == 8) ? 3 : (chunk == 4) ? 2 : (chunk == 2) ? 1 : 0;

  dim3 blk(256);

  // weight prep
  wprep_k<<<720, blk, 0, stream>>>(rw1, WH + W_res1, WL + W_res1, 64, 64, 5);
  wprep_k<<<720, blk, 0, stream>>>(rw2, WH + W_res2, WL + W_res2, 64, 64, 5);
  wprep_k<<<288, blk, 0, stream>>>(crw, WH + W_cr, WL + W_cr, 64, 128, 1);
  wprep_k<<<1296, blk, 0, stream>>>(ofw, WH + W_off, WL + W_off, 144, 64, 4);
  dwprep_k<<<576, blk, 0, stream>>>(dcw, DH, DL);

  // conv_first + ReLU : x (10,3,HW) -> A (10,64,HW)   [VALU fp32, CIN=3]
  conv3x3_k<3, 3, 16, true, false><<<dim3(4, 4, 40), blk, 0, stream>>>(
      x, cfw, cfb, nullptr, A, 64, 4, 0, 0);

  // 5 residual blocks (split-fp16 MFMA, full 64 oc per block)
  for (int i = 0; i < 5; ++i) {
    conv_mfma_k<2, 4, true, false, false><<<dim3(4, 16, 10), blk, 0, stream>>>(
        A, WH + W_res1 + (long)i * 36864, WL + W_res1 + (long)i * 36864,
        rb1 + i * 64, nullptr, r, 64, 1, 0, 0);
    conv_mfma_k<2, 4, false, true, false><<<dim3(4, 16, 10), blk, 0, stream>>>(
        r, WH + W_res2 + (long)i * 36864, WL + W_res2 + (long)i * 36864,
        rb2 + i * 64, A, A, 64, 1, 0, 0);
  }

  // cr conv, fused concat(ref,supp): A -> C (fea0)
  conv_mfma_k<4, 4, false, false, true><<<dim3(4, 16, 8), blk, 0, stream>>>(
      A, WH + W_cr, WL + W_cr, crb, nullptr, C, 64, 1, 0, 0);

  // offset conv (split-fp16 MFMA, 144ch = 3x48) + deform (MFMA v3), chunked
  auto off_deform = [&](const float* fea_in, const float* grouped,
                        int layer, float* outp) {
    for (int i0 = 0; i0 < 8; i0 += chunk) {
      conv_mfma_k<2, 3, false, false, false>
          <<<dim3(4, 16, chunk * 3), blk, 0, stream>>>(
              fea_in, WH + W_off + (long)layer * 82944,
              WL + W_off + (long)layer * 82944, ofb + layer * 144,
              nullptr, OFF, 144, 3, i0, 0);
      deform_mfma_k<<<dim3(256 * chunk), blk, 0, stream>>>(
          grouped, OFF, DH + (long)layer * 36864, DL + (long)layer * 36864,
          outp, i0, chunk - 1, cshift);
    }
  };

  // layer 0: fea1 = deform(fea0, conv(fea0))        C -> C
  regroup_k<<<32768, blk, 0, stream>>>(C, D, 0);
  off_deform(C, D, 0, C);

  // layer 1: fea2 = deform(fea1, conv(fea1))        C -> C
  regroup_k<<<32768, blk, 0, stream>>>(C, D, 0);
  off_deform(C, D, 1, C);

  // layer 2: fea3 = deform(supp, conv(fea2))        (A supp, C) -> F
  regroup_k<<<32768, blk, 0, stream>>>(A, D, 1);
  off_deform(C, D, 2, F);

  // layer 3: aligned = deform(fea3, conv(fea3))     F -> C
  regroup_k<<<32768, blk, 0, stream>>>(F, D, 0);
  off_deform(F, D, 3, C);

  // recon conv: aligned -> im (8,3,HW)   [VALU fp32, Cout=3]
  conv3x3_k<64, 8, 4, false, false><<<dim3(4, 4, 8), blk, 0, stream>>>(
      C, rcw, rcb, nullptr, im, 3, 1, 0, 0);

  // assemble outputs
  assemble_k<<<42880, blk, 0, stream>>>(x, im, A, F, out);
}